// Round 1
// baseline (2310.078 us; speedup 1.0000x reference)
//
#include <hip/hip_runtime.h>
#include <hip/hip_bf16.h>

// Problem constants (from reference)
#define Bb 4
#define Ss 2048
#define Hh 1024
#define Mm 1024
#define NHh 16
#define DHh 64
#define CRr 4
#define Ll (Ss / CRr)          // 512

// ---------------------------------------------------------------------------
// Generic tiled FP32 GEMM: C[M x N] = act(A_cat[M x K] @ W[K x N] + bias)
// A_cat: columns [0,K1) from A (row stride K1), columns [K1,K) from A2
// (row stride K-K1).  act: 0 = none, 1 = SiLU.
// BM=64, BN=64, BK=16, 256 threads, 4x4 accum per thread.
// ---------------------------------------------------------------------------
#define BM 64
#define BN 64
#define BK 16

__global__ __launch_bounds__(256) void gemm_kernel(
    const float* __restrict__ A, const float* __restrict__ A2, int K1,
    const float* __restrict__ W, const float* __restrict__ bias,
    float* __restrict__ C, int Mdim, int Ndim, int Kdim, int act)
{
    __shared__ float As[BK][BM];   // [k][m]
    __shared__ float Ws[BK][BN];   // [k][n]

    const int t  = threadIdx.x;
    const int tx = t % 16;
    const int ty = t / 16;
    const int bm = blockIdx.y * BM;
    const int bn = blockIdx.x * BN;

    float acc[4][4] = {};

    const int ar = t / 4;         // 0..63  (A tile row)
    const int ak = (t % 4) * 4;   // 0,4,8,12 (A tile k)
    const int wk = t / 16;        // 0..15  (W tile k)
    const int wn = (t % 16) * 4;  // W tile n

    const int K2 = Kdim - K1;

    for (int k0 = 0; k0 < Kdim; k0 += BK) {
        // ---- load A tile (store transposed As[k][m]) ----
        {
            const int gr = bm + ar;
            const int gk = k0 + ak;
            const float* src = (gk < K1)
                ? (A  + (size_t)gr * K1 + gk)
                : (A2 + (size_t)gr * K2 + (gk - K1));
            float4 av = *reinterpret_cast<const float4*>(src);
            As[ak + 0][ar] = av.x;
            As[ak + 1][ar] = av.y;
            As[ak + 2][ar] = av.z;
            As[ak + 3][ar] = av.w;
        }
        // ---- load W tile ----
        {
            float4 wv = *reinterpret_cast<const float4*>(
                W + (size_t)(k0 + wk) * Ndim + bn + wn);
            *reinterpret_cast<float4*>(&Ws[wk][wn]) = wv;
        }
        __syncthreads();

        #pragma unroll
        for (int kk = 0; kk < BK; ++kk) {
            float4 ra = *reinterpret_cast<const float4*>(&As[kk][ty * 4]);
            float4 rw = *reinterpret_cast<const float4*>(&Ws[kk][tx * 4]);
            float a_[4] = {ra.x, ra.y, ra.z, ra.w};
            float w_[4] = {rw.x, rw.y, rw.z, rw.w};
            #pragma unroll
            for (int i = 0; i < 4; ++i)
                #pragma unroll
                for (int j = 0; j < 4; ++j)
                    acc[i][j] += a_[i] * w_[j];
        }
        __syncthreads();
    }

    #pragma unroll
    for (int i = 0; i < 4; ++i) {
        const int row = bm + ty * 4 + i;
        #pragma unroll
        for (int j = 0; j < 4; ++j) {
            const int col = bn + tx * 4 + j;
            float c = acc[i][j] + bias[col];
            if (act == 1) c = c / (1.0f + __expf(-c));   // SiLU
            C[(size_t)row * Ndim + col] = c;
        }
    }
}

// ---------------------------------------------------------------------------
// Flash-style attention.  grid = (S/64, NH, B), block = 256 (16x16 logical).
// Each block: 64 queries of one (b,h); loops over 16 chunks of 64 keys.
// q,k,v are [rows][H] with head h at columns h*64..h*64+63.
// out (retrieved, pre-Wo) written as [B*S][H].
// ---------------------------------------------------------------------------
__global__ __launch_bounds__(256) void attn_kernel(
    const float* __restrict__ q, const float* __restrict__ k,
    const float* __restrict__ v, const unsigned char* __restrict__ mask,
    float* __restrict__ out)
{
    const int qt = blockIdx.x, h = blockIdx.y, b = blockIdx.z;
    const int t  = threadIdx.x;
    const int tx = t % 16;
    const int ty = t / 16;

    __shared__ float qs[64][65];
    __shared__ float ks[64][65];
    __shared__ float vs[64][65];
    __shared__ float ps[64][65];

    // load q tile
    {
        const int d4 = (t % 16) * 4;
        #pragma unroll
        for (int it = 0; it < 4; ++it) {
            const int r = it * 16 + t / 16;
            float4 qv = *reinterpret_cast<const float4*>(
                q + ((size_t)(b * Ss + qt * 64 + r)) * Hh + h * 64 + d4);
            qs[r][d4 + 0] = qv.x; qs[r][d4 + 1] = qv.y;
            qs[r][d4 + 2] = qv.z; qs[r][d4 + 3] = qv.w;
        }
    }

    float m_run[4], l_run[4];
    float acc[4][4] = {};
    #pragma unroll
    for (int i = 0; i < 4; ++i) { m_run[i] = -3.0e38f; l_run[i] = 0.0f; }

    const float scale = 0.125f;   // 1/sqrt(64)

    for (int c = 0; c < Mm / 64; ++c) {
        __syncthreads();          // previous iter done with ks/vs/ps
        // ---- load K,V chunk ----
        {
            const int d4 = (t % 16) * 4;
            #pragma unroll
            for (int it = 0; it < 4; ++it) {
                const int r = it * 16 + t / 16;
                const size_t off =
                    ((size_t)(b * Mm + c * 64 + r)) * Hh + h * 64 + d4;
                float4 kv = *reinterpret_cast<const float4*>(k + off);
                ks[r][d4 + 0] = kv.x; ks[r][d4 + 1] = kv.y;
                ks[r][d4 + 2] = kv.z; ks[r][d4 + 3] = kv.w;
                float4 vv = *reinterpret_cast<const float4*>(v + off);
                vs[r][d4 + 0] = vv.x; vs[r][d4 + 1] = vv.y;
                vs[r][d4 + 2] = vv.z; vs[r][d4 + 3] = vv.w;
            }
        }
        __syncthreads();

        // ---- scores: s[i][j] = q[ty*4+i] . k[tx*4+j] ----
        float s[4][4] = {};
        for (int d = 0; d < 64; ++d) {
            float a0 = qs[ty * 4 + 0][d], a1 = qs[ty * 4 + 1][d];
            float a2 = qs[ty * 4 + 2][d], a3 = qs[ty * 4 + 3][d];
            float b0 = ks[tx * 4 + 0][d], b1 = ks[tx * 4 + 1][d];
            float b2 = ks[tx * 4 + 2][d], b3 = ks[tx * 4 + 3][d];
            s[0][0] += a0 * b0; s[0][1] += a0 * b1; s[0][2] += a0 * b2; s[0][3] += a0 * b3;
            s[1][0] += a1 * b0; s[1][1] += a1 * b1; s[1][2] += a1 * b2; s[1][3] += a1 * b3;
            s[2][0] += a2 * b0; s[2][1] += a2 * b1; s[2][2] += a2 * b2; s[2][3] += a2 * b3;
            s[3][0] += a3 * b0; s[3][1] += a3 * b1; s[3][2] += a3 * b2; s[3][3] += a3 * b3;
        }
        // mask + scale
        #pragma unroll
        for (int j = 0; j < 4; ++j) {
            const bool mk = mask[b * Mm + c * 64 + tx * 4 + j] != 0;
            #pragma unroll
            for (int i = 0; i < 4; ++i)
                s[i][j] = mk ? s[i][j] * scale : -3.0e38f;
        }
        // online softmax per row (rows shared by the 16 tx-lanes of a group)
        #pragma unroll
        for (int i = 0; i < 4; ++i) {
            float mx = fmaxf(fmaxf(s[i][0], s[i][1]), fmaxf(s[i][2], s[i][3]));
            #pragma unroll
            for (int o = 1; o < 16; o <<= 1) mx = fmaxf(mx, __shfl_xor(mx, o, 16));
            const float m_new = fmaxf(m_run[i], mx);
            const float fac   = __expf(m_run[i] - m_new);  // 0 if m_run=-3e38
            float psum = 0.0f;
            #pragma unroll
            for (int j = 0; j < 4; ++j) {
                float p = (s[i][j] <= -1.0e37f) ? 0.0f : __expf(s[i][j] - m_new);
                s[i][j] = p;
                psum += p;
            }
            #pragma unroll
            for (int o = 1; o < 16; o <<= 1) psum += __shfl_xor(psum, o, 16);
            l_run[i] = l_run[i] * fac + psum;
            m_run[i] = m_new;
            #pragma unroll
            for (int j = 0; j < 4; ++j) acc[i][j] *= fac;
            #pragma unroll
            for (int j = 0; j < 4; ++j) ps[ty * 4 + i][tx * 4 + j] = s[i][j];
        }
        __syncthreads();

        // ---- PV: acc[i][j] += P[row][kk] * V[kk][col] ----
        for (int kk = 0; kk < 64; ++kk) {
            float p0 = ps[ty * 4 + 0][kk], p1 = ps[ty * 4 + 1][kk];
            float p2 = ps[ty * 4 + 2][kk], p3 = ps[ty * 4 + 3][kk];
            float v0 = vs[kk][tx * 4 + 0], v1 = vs[kk][tx * 4 + 1];
            float v2 = vs[kk][tx * 4 + 2], v3 = vs[kk][tx * 4 + 3];
            acc[0][0] += p0 * v0; acc[0][1] += p0 * v1; acc[0][2] += p0 * v2; acc[0][3] += p0 * v3;
            acc[1][0] += p1 * v0; acc[1][1] += p1 * v1; acc[1][2] += p1 * v2; acc[1][3] += p1 * v3;
            acc[2][0] += p2 * v0; acc[2][1] += p2 * v1; acc[2][2] += p2 * v2; acc[2][3] += p2 * v3;
            acc[3][0] += p3 * v0; acc[3][1] += p3 * v1; acc[3][2] += p3 * v2; acc[3][3] += p3 * v3;
        }
    }

    #pragma unroll
    for (int i = 0; i < 4; ++i) {
        const float inv = (l_run[i] > 0.0f) ? 1.0f / l_run[i] : 0.0f;
        const int row = b * Ss + qt * 64 + ty * 4 + i;
        #pragma unroll
        for (int j = 0; j < 4; ++j) {
            const int col = h * 64 + tx * 4 + j;
            out[(size_t)row * Hh + col] = acc[i][j] * inv;
        }
    }
}

// ---------------------------------------------------------------------------
// Gate head: g[row] = sigmoid( h[row,0:512] . w2 + b2 ).  1 wave per row.
// ---------------------------------------------------------------------------
__global__ __launch_bounds__(256) void gate2_kernel(
    const float* __restrict__ h, const float* __restrict__ w2,
    const float* __restrict__ b2, float* __restrict__ outg, int R)
{
    const int wid  = threadIdx.x / 64;
    const int lane = threadIdx.x % 64;
    const int row  = blockIdx.x * 4 + wid;
    if (row >= R) return;
    const float* hr = h + (size_t)row * 512;
    float s = 0.0f;
    #pragma unroll
    for (int i = 0; i < 8; ++i) s += hr[lane + i * 64] * w2[lane + i * 64];
    #pragma unroll
    for (int o = 1; o < 64; o <<= 1) s += __shfl_xor(s, o);
    if (lane == 0) outg[row] = 1.0f / (1.0f + __expf(-(s + b2[0])));
}

// ---------------------------------------------------------------------------
// out = LayerNorm(hs + rg*retr) * g + b.  1 block (256 thr) per row of H=1024.
// ---------------------------------------------------------------------------
__global__ __launch_bounds__(256) void out_ln_kernel(
    const float* __restrict__ hs, const float* __restrict__ retr,
    const float* __restrict__ rg, const float* __restrict__ gam,
    const float* __restrict__ bet, float* __restrict__ out)
{
    const int row = blockIdx.x;
    const int t = threadIdx.x;
    const float r = rg[row];
    float x[4];
    float s = 0.0f, s2 = 0.0f;
    #pragma unroll
    for (int i = 0; i < 4; ++i) {
        const int col = t + i * 256;
        const float val = hs[(size_t)row * Hh + col] + r * retr[(size_t)row * Hh + col];
        x[i] = val; s += val; s2 += val * val;
    }
    #pragma unroll
    for (int o = 1; o < 64; o <<= 1) { s += __shfl_xor(s, o); s2 += __shfl_xor(s2, o); }
    __shared__ float rs[4], rs2[4];
    const int wid = t / 64, lane = t % 64;
    if (lane == 0) { rs[wid] = s; rs2[wid] = s2; }
    __syncthreads();
    const float tot  = rs[0] + rs[1] + rs[2] + rs[3];
    const float tot2 = rs2[0] + rs2[1] + rs2[2] + rs2[3];
    const float mu   = tot * (1.0f / Hh);
    const float var  = tot2 * (1.0f / Hh) - mu * mu;
    const float rstd = rsqrtf(var + 1e-5f);
    #pragma unroll
    for (int i = 0; i < 4; ++i) {
        const int col = t + i * 256;
        out[(size_t)row * Hh + col] = (x[i] - mu) * rstd * gam[col] + bet[col];
    }
}

// ---------------------------------------------------------------------------
// wg_L[i] = mean of wg_row[4i..4i+3]
// ---------------------------------------------------------------------------
__global__ void wgmean_kernel(const float* __restrict__ wg_row,
                              float* __restrict__ wg_L)
{
    const int i = blockIdx.x * 256 + threadIdx.x;
    if (i < Bb * Ll)
        wg_L[i] = 0.25f * (wg_row[4 * i] + wg_row[4 * i + 1] +
                           wg_row[4 * i + 2] + wg_row[4 * i + 3]);
}

// ---------------------------------------------------------------------------
// Scatter gated compressed rows into the circular buffer of bank_out.
// grid = B*L blocks, 256 threads (float4 per thread over H).
// ---------------------------------------------------------------------------
__global__ __launch_bounds__(256) void scatter_kernel(
    const float* __restrict__ comp, const float* __restrict__ wgL,
    const int* __restrict__ wp_ptr, float* __restrict__ bank_out)
{
    const int row = blockIdx.x;            // 0..B*L-1
    const int b = row / Ll, l = row % Ll;
    const int wp = *wp_ptr;
    const int m = (wp + l) % Mm;
    const float g = wgL[row];
    const int col = threadIdx.x * 4;
    float4 cv = *reinterpret_cast<const float4*>(comp + (size_t)row * Hh + col);
    cv.x *= g; cv.y *= g; cv.z *= g; cv.w *= g;
    *reinterpret_cast<float4*>(bank_out + ((size_t)(b * Mm + m)) * Hh + col) = cv;
}

// ---------------------------------------------------------------------------
// new_mask (as float 0/1) and new_ptr (as float)
// ---------------------------------------------------------------------------
__global__ void maskptr_kernel(const unsigned char* __restrict__ mask,
                               const int* __restrict__ wp_ptr,
                               float* __restrict__ mask_out,
                               float* __restrict__ ptr_out)
{
    const int i = blockIdx.x * 256 + threadIdx.x;
    const int wp = *wp_ptr;
    if (i < Bb * Mm) {
        const int m = i % Mm;
        int rel = m - (wp % Mm);
        if (rel < 0) rel += Mm;
        const bool written = rel < Ll;
        mask_out[i] = (mask[i] != 0 || written) ? 1.0f : 0.0f;
    }
    if (i == 0) ptr_out[0] = (float)((wp + Ll) % Mm);
}

// ---------------------------------------------------------------------------
// Launch
// ---------------------------------------------------------------------------
extern "C" void kernel_launch(void* const* d_in, const int* in_sizes, int n_in,
                              void* d_out, int out_size, void* d_ws, size_t ws_size,
                              hipStream_t stream)
{
    const float* hs   = (const float*)d_in[0];
    const float* bank = (const float*)d_in[1];
    const unsigned char* mask = (const unsigned char*)d_in[2];
    const int*   wp   = (const int*)d_in[3];
    const float* Wc1 = (const float*)d_in[4];  const float* bc1 = (const float*)d_in[5];
    const float* Wc2 = (const float*)d_in[6];  const float* bc2 = (const float*)d_in[7];
    const float* Wq  = (const float*)d_in[8];  const float* bq  = (const float*)d_in[9];
    const float* Wk  = (const float*)d_in[10]; const float* bk  = (const float*)d_in[11];
    const float* Wv  = (const float*)d_in[12]; const float* bv  = (const float*)d_in[13];
    const float* Wo  = (const float*)d_in[14]; const float* bo  = (const float*)d_in[15];
    const float* Wwg1 = (const float*)d_in[16]; const float* bwg1 = (const float*)d_in[17];
    const float* Wwg2 = (const float*)d_in[18]; const float* bwg2 = (const float*)d_in[19];
    const float* Wrg1 = (const float*)d_in[20]; const float* brg1 = (const float*)d_in[21];
    const float* Wrg2 = (const float*)d_in[22]; const float* brg2 = (const float*)d_in[23];
    const float* ln_g = (const float*)d_in[24]; const float* ln_b = (const float*)d_in[25];

    // output layout (floats): out | new_bank | new_mask | new_ptr
    float* out_main  = (float*)d_out;                              // B*S*H
    float* out_bank  = out_main + (size_t)Bb * Ss * Hh;            // B*M*H
    float* out_mask  = out_bank + (size_t)Bb * Mm * Hh;            // B*M
    float* out_ptr   = out_mask + (size_t)Bb * Mm;                 // 1

    // workspace layout (floats), with reuse
    float* ws = (float*)d_ws;
    float* qb      = ws;                         // 8M   [B*S, H]
    float* kb      = ws + 8388608;               // 4M   [B*M, H]
    float* vb      = ws + 12582912;              // 4M   [B*M, H]
    float* att     = ws + 16777216;              // 8M   [B*S, H]
    float* retr    = ws;                         // reuse qb after attention
    float* rg_h    = ws + 8388608;               // reuse kb/vb   [B*S, 512]
    float* rg      = ws + 12582912;              // 8192
    float* wg_h    = ws + 8388608;               // reuse rg_h after rg done
    float* wg_row  = ws + 12582912 + 8192;       // 8192
    float* wg_L    = ws + 12582912 + 16384;      // 2048
    float* comp_h  = ws + 16777216;              // reuse att    [B*L, H]
    float* comp    = ws + 16777216 + 2097152;    // [B*L, H]

    const int R = Bb * Ss;   // 8192 token rows

    // 1) Q,K,V projections
    gemm_kernel<<<dim3(Hh / BN, R / BM), 256, 0, stream>>>(
        hs, hs, Hh, Wq, bq, qb, R, Hh, Hh, 0);
    gemm_kernel<<<dim3(Hh / BN, (Bb * Mm) / BM), 256, 0, stream>>>(
        bank, bank, Hh, Wk, bk, kb, Bb * Mm, Hh, Hh, 0);
    gemm_kernel<<<dim3(Hh / BN, (Bb * Mm) / BM), 256, 0, stream>>>(
        bank, bank, Hh, Wv, bv, vb, Bb * Mm, Hh, Hh, 0);

    // 2) attention
    attn_kernel<<<dim3(Ss / 64, NHh, Bb), 256, 0, stream>>>(qb, kb, vb, mask, att);

    // 3) output projection
    gemm_kernel<<<dim3(Hh / BN, R / BM), 256, 0, stream>>>(
        att, att, Hh, Wo, bo, retr, R, Hh, Hh, 0);

    // 4) read gate: silu(concat(hs, retr) @ Wrg1 + brg1) -> rg_h ; head -> rg
    gemm_kernel<<<dim3(512 / BN, R / BM), 256, 0, stream>>>(
        hs, retr, Hh, Wrg1, brg1, rg_h, R, 512, 2 * Hh, 1);
    gate2_kernel<<<R / 4, 256, 0, stream>>>(rg_h, Wrg2, brg2, rg, R);

    // 5) residual + layernorm -> out_main
    out_ln_kernel<<<R, 256, 0, stream>>>(hs, retr, rg, ln_g, ln_b, out_main);

    // 6) write gate
    gemm_kernel<<<dim3(512 / BN, R / BM), 256, 0, stream>>>(
        hs, hs, Hh, Wwg1, bwg1, wg_h, R, 512, Hh, 1);
    gate2_kernel<<<R / 4, 256, 0, stream>>>(wg_h, Wwg2, bwg2, wg_row, R);
    wgmean_kernel<<<(Bb * Ll + 255) / 256, 256, 0, stream>>>(wg_row, wg_L);

    // 7) compressor: hs viewed as [B*L, CR*H]
    gemm_kernel<<<dim3(Hh / BN, (Bb * Ll) / BM), 256, 0, stream>>>(
        hs, hs, CRr * Hh, Wc1, bc1, comp_h, Bb * Ll, Hh, CRr * Hh, 1);
    gemm_kernel<<<dim3(Hh / BN, (Bb * Ll) / BM), 256, 0, stream>>>(
        comp_h, comp_h, Hh, Wc2, bc2, comp, Bb * Ll, Hh, Hh, 0);

    // 8) new_bank = bank copy, then scatter gated rows
    hipMemcpyAsync(out_bank, bank, (size_t)Bb * Mm * Hh * sizeof(float),
                   hipMemcpyDeviceToDevice, stream);
    scatter_kernel<<<Bb * Ll, 256, 0, stream>>>(comp, wg_L, wp, out_bank);

    // 9) mask + pointer
    maskptr_kernel<<<(Bb * Mm + 255) / 256, 256, 0, stream>>>(
        mask, wp, out_mask, out_ptr);
}

// Round 2
// 660.275 us; speedup vs baseline: 3.4987x; 3.4987x over previous
//
#include <hip/hip_runtime.h>
#include <hip/hip_bf16.h>

// Problem constants
#define Bb 4
#define Ss 2048
#define Hh 1024
#define Mm 1024
#define NHh 16
#define DHh 64
#define CRr 4
#define Ll (Ss / CRr)          // 512

typedef __attribute__((ext_vector_type(8))) short short8;   // 8 bf16 (4 VGPRs)
typedef __attribute__((ext_vector_type(4))) float f32x4;

typedef __attribute__((address_space(1))) const unsigned int g_u32;
typedef __attribute__((address_space(3))) unsigned int l_u32;

__device__ inline void gload_lds16(const void* g, void* l) {
    __builtin_amdgcn_global_load_lds((g_u32*)g, (l_u32*)l, 16, 0, 0);
}

__device__ inline unsigned short f2bf(float x) {
    unsigned int u = __builtin_bit_cast(unsigned int, x);
    unsigned int r = u + 0x7FFFu + ((u >> 16) & 1u);   // RNE
    return (unsigned short)(r >> 16);
}
__device__ inline float bf2f(unsigned short u) {
    return __builtin_bit_cast(float, (unsigned int)u << 16);
}

// ---------------------------------------------------------------------------
// f32 -> bf16 elementwise cast (8 elems / thread)
// ---------------------------------------------------------------------------
__global__ __launch_bounds__(256) void cast_bf16_kernel(
    const float* __restrict__ in, unsigned short* __restrict__ out, int n8)
{
    const int i = blockIdx.x * 256 + threadIdx.x;
    if (i >= n8) return;
    const float4* p = reinterpret_cast<const float4*>(in) + (size_t)i * 2;
    float4 a = p[0], b = p[1];
    uint4 o;
    o.x = (unsigned)f2bf(a.x) | ((unsigned)f2bf(a.y) << 16);
    o.y = (unsigned)f2bf(a.z) | ((unsigned)f2bf(a.w) << 16);
    o.z = (unsigned)f2bf(b.x) | ((unsigned)f2bf(b.y) << 16);
    o.w = (unsigned)f2bf(b.z) | ((unsigned)f2bf(b.w) << 16);
    *reinterpret_cast<uint4*>(out + (size_t)i * 8) = o;
}

// ---------------------------------------------------------------------------
// W[K][N] f32  ->  Wt[N][K] bf16  (transpose + cast), 32x32 tiles
// ---------------------------------------------------------------------------
__global__ __launch_bounds__(256) void transpose_cast_kernel(
    const float* __restrict__ W, unsigned short* __restrict__ Wt, int K, int N)
{
    __shared__ float tile[32][33];
    const int k0 = blockIdx.y * 32, n0 = blockIdx.x * 32;
    const int tx = threadIdx.x & 31, ty = threadIdx.x >> 5;   // ty 0..7
    #pragma unroll
    for (int r = 0; r < 32; r += 8)
        tile[r + ty][tx] = W[(size_t)(k0 + r + ty) * N + n0 + tx];
    __syncthreads();
    #pragma unroll
    for (int r = 0; r < 32; r += 8)
        Wt[(size_t)(n0 + r + ty) * K + k0 + tx] = f2bf(tile[tx][r + ty]);
}

// ---------------------------------------------------------------------------
// BF16 MFMA GEMM (NT): C[M][N] = act( Acat[M][K] @ Wt[N][K]^T + bias )
//   Acat: k in [0,K1) from A1 (row stride K1), k in [K1,K) from A2.
//   Tile 128x128, BK=64, 4 waves, each wave 64x64 via 4x4 16x16x32 MFMAs.
//   LDS staged with global_load_lds(16B) + XOR chunk swizzle (both sides).
//   Outputs: Cf (fp32) and/or Cb (bf16); act: 0 none, 1 SiLU.
// ---------------------------------------------------------------------------
__global__ __launch_bounds__(256) void gemm_bf16_kernel(
    const unsigned short* __restrict__ A1, const unsigned short* __restrict__ A2,
    int K1, const unsigned short* __restrict__ Wt, const float* __restrict__ bias,
    float* __restrict__ Cf, unsigned short* __restrict__ Cb,
    int Mdim, int Ndim, int Kdim, int act)
{
    __shared__ __align__(16) unsigned short As[128 * 64];
    __shared__ __align__(16) unsigned short Bs[128 * 64];

    const int t = threadIdx.x;
    const int l = t & 63;
    const int w = t >> 6;
    const int bm = blockIdx.y * 128;
    const int bn = blockIdx.x * 128;
    const int m_off = (w >> 1) * 64;
    const int n_off = (w & 1) * 64;
    const int K2 = Kdim - K1;

    f32x4 acc[4][4];
    const f32x4 z = {0.f, 0.f, 0.f, 0.f};
    #pragma unroll
    for (int i = 0; i < 4; ++i)
        #pragma unroll
        for (int j = 0; j < 4; ++j) acc[i][j] = z;

    for (int kt = 0; kt < Kdim; kt += 64) {
        __syncthreads();
        // ---- stage A,B tiles: 1024 chunks of 16B each, swizzled ----
        const unsigned short* Ap; int rsA, kl;
        if (kt < K1) { Ap = A1; rsA = K1; kl = kt; }
        else         { Ap = A2; rsA = K2; kl = kt - K1; }
        #pragma unroll
        for (int i = 0; i < 4; ++i) {
            const int c = i * 256 + t;
            const int row = c >> 3;
            const int p = (c & 7) ^ (row & 7);
            gload_lds16(Ap + (size_t)(bm + row) * rsA + kl + p * 8,
                        (char*)As + c * 16);
            gload_lds16(Wt + (size_t)(bn + row) * Kdim + kt + p * 8,
                        (char*)Bs + c * 16);
        }
        __syncthreads();
        // ---- compute ----
        #pragma unroll
        for (int kk = 0; kk < 2; ++kk) {
            short8 af[4], bfr[4];
            #pragma unroll
            for (int i = 0; i < 4; ++i) {
                const int ra = m_off + i * 16 + (l & 15);
                af[i] = *(const short8*)((const char*)As + ra * 128 +
                          (((kk * 4 + (l >> 4)) ^ (ra & 7)) * 16));
                const int rb = n_off + i * 16 + (l & 15);
                bfr[i] = *(const short8*)((const char*)Bs + rb * 128 +
                          (((kk * 4 + (l >> 4)) ^ (rb & 7)) * 16));
            }
            #pragma unroll
            for (int i = 0; i < 4; ++i)
                #pragma unroll
                for (int j = 0; j < 4; ++j)
                    acc[i][j] = __builtin_amdgcn_mfma_f32_16x16x32_bf16(
                        af[i], bfr[j], acc[i][j], 0, 0, 0);
        }
    }

    // ---- epilogue: C row = bm+m_off+i*16+(l>>4)*4+r, col = bn+n_off+j*16+(l&15)
    #pragma unroll
    for (int j = 0; j < 4; ++j) {
        const int col = bn + n_off + j * 16 + (l & 15);
        const float bj = bias[col];
        #pragma unroll
        for (int i = 0; i < 4; ++i)
            #pragma unroll
            for (int r = 0; r < 4; ++r) {
                const int row = bm + m_off + i * 16 + (l >> 4) * 4 + r;
                float v0 = acc[i][j][r] + bj;
                if (act == 1) v0 = v0 / (1.0f + __expf(-v0));
                if (Cf) Cf[(size_t)row * Ndim + col] = v0;
                if (Cb) Cb[(size_t)row * Ndim + col] = f2bf(v0);
            }
    }
}

// ---------------------------------------------------------------------------
// Flash attention, bf16 MFMA.  grid=(S/64, NH, B), 256 thr (4 waves).
// Wave w owns query rows w*16..w*16+15 of the 64-row Q tile.
// LDS tiles padded to 72 bf16/row (no swizzle needed; reg-staged).
// ---------------------------------------------------------------------------
__global__ __launch_bounds__(256) void attn_bf16_kernel(
    const unsigned short* __restrict__ q, const unsigned short* __restrict__ k,
    const unsigned short* __restrict__ v, const unsigned char* __restrict__ mask,
    unsigned short* __restrict__ out)
{
    const int qt = blockIdx.x, h = blockIdx.y, b = blockIdx.z;
    const int t = threadIdx.x, l = t & 63, w = t >> 6;

    __shared__ __align__(16) unsigned short Qs[64][72];
    __shared__ __align__(16) unsigned short Ks[64][72];
    __shared__ __align__(16) unsigned short Vt[64][72];   // [d][key]
    __shared__ __align__(16) unsigned short Ps[64][72];

    // ---- load Q tile (copy bf16) ----
    {
        const int row = t >> 2, dblk = (t & 3) * 16;
        const unsigned short* src =
            q + ((size_t)(b * Ss + qt * 64 + row)) * Hh + h * 64 + dblk;
        uint4 a = *(const uint4*)(src);
        uint4 c2 = *(const uint4*)(src + 8);
        *(uint4*)&Qs[row][dblk] = a;
        *(uint4*)&Qs[row][dblk + 8] = c2;
    }

    const f32x4 z = {0.f, 0.f, 0.f, 0.f};
    f32x4 oa[4];
    #pragma unroll
    for (int j = 0; j < 4; ++j) oa[j] = z;
    float m_run[4], l_run[4];
    #pragma unroll
    for (int r = 0; r < 4; ++r) { m_run[r] = -3.0e38f; l_run[r] = 0.0f; }

    for (int c = 0; c < Mm / 64; ++c) {
        __syncthreads();   // prev iter done with Ks/Vt (and Qs writes on c==0)
        // ---- stage K chunk + V^T chunk ----
        {
            const int row = t >> 2, dblk = (t & 3) * 16;
            const size_t off =
                ((size_t)(b * Mm + c * 64 + row)) * Hh + h * 64 + dblk;
            uint4 a = *(const uint4*)(k + off);
            uint4 c2 = *(const uint4*)(k + off + 8);
            *(uint4*)&Ks[row][dblk] = a;
            *(uint4*)&Ks[row][dblk + 8] = c2;
            // V: row = key, transpose into Vt[d][key]
            uint4 va = *(const uint4*)(v + off);
            uint4 vb = *(const uint4*)(v + off + 8);
            unsigned short e[16];
            *(uint4*)&e[0] = va;
            *(uint4*)&e[8] = vb;
            #pragma unroll
            for (int j = 0; j < 16; ++j) Vt[dblk + j][row] = e[j];
        }
        __syncthreads();

        // ---- S = Q K^T for this wave's 16 rows x 64 keys ----
        f32x4 sa[4];
        #pragma unroll
        for (int nt = 0; nt < 4; ++nt) sa[nt] = z;
        #pragma unroll
        for (int kk = 0; kk < 2; ++kk) {
            short8 qa = *(const short8*)&Qs[w * 16 + (l & 15)][kk * 32 + (l >> 4) * 8];
            #pragma unroll
            for (int nt = 0; nt < 4; ++nt) {
                short8 kb = *(const short8*)&Ks[nt * 16 + (l & 15)][kk * 32 + (l >> 4) * 8];
                sa[nt] = __builtin_amdgcn_mfma_f32_16x16x32_bf16(qa, kb, sa[nt], 0, 0, 0);
            }
        }

        // ---- mask + scale ----
        float sv[4][4];   // [nt][r]
        bool mk[4];
        #pragma unroll
        for (int nt = 0; nt < 4; ++nt) {
            mk[nt] = mask[b * Mm + c * 64 + nt * 16 + (l & 15)] != 0;
            #pragma unroll
            for (int r = 0; r < 4; ++r)
                sv[nt][r] = mk[nt] ? sa[nt][r] * 0.125f : -3.0e38f;
        }

        // ---- online softmax (rows live in 16-lane groups) ----
        float facs[4];
        #pragma unroll
        for (int r = 0; r < 4; ++r) {
            float mx = fmaxf(fmaxf(sv[0][r], sv[1][r]), fmaxf(sv[2][r], sv[3][r]));
            #pragma unroll
            for (int o = 1; o < 16; o <<= 1) mx = fmaxf(mx, __shfl_xor(mx, o, 16));
            const float m_new = fmaxf(m_run[r], mx);
            const float fac = __expf(m_run[r] - m_new);
            float psum = 0.0f;
            #pragma unroll
            for (int nt = 0; nt < 4; ++nt) {
                const float p = mk[nt] ? __expf(sv[nt][r] - m_new) : 0.0f;
                sv[nt][r] = p;
                psum += p;
            }
            #pragma unroll
            for (int o = 1; o < 16; o <<= 1) psum += __shfl_xor(psum, o, 16);
            l_run[r] = l_run[r] * fac + psum;
            m_run[r] = m_new;
            facs[r] = fac;
            // write P row (bf16): q = w*16 + (l>>4)*4 + r, key = nt*16 + (l&15)
            #pragma unroll
            for (int nt = 0; nt < 4; ++nt)
                Ps[w * 16 + (l >> 4) * 4 + r][nt * 16 + (l & 15)] = f2bf(sv[nt][r]);
        }
        __syncthreads();   // Ps ordering

        // ---- rescale + PV ----
        #pragma unroll
        for (int j = 0; j < 4; ++j)
            #pragma unroll
            for (int r = 0; r < 4; ++r) oa[j][r] *= facs[r];
        #pragma unroll
        for (int kk = 0; kk < 2; ++kk) {
            short8 pa = *(const short8*)&Ps[w * 16 + (l & 15)][kk * 32 + (l >> 4) * 8];
            #pragma unroll
            for (int jt = 0; jt < 4; ++jt) {
                short8 vb = *(const short8*)&Vt[jt * 16 + (l & 15)][kk * 32 + (l >> 4) * 8];
                oa[jt] = __builtin_amdgcn_mfma_f32_16x16x32_bf16(pa, vb, oa[jt], 0, 0, 0);
            }
        }
    }

    // ---- output: att_bf[row][h*64 + jt*16 + (l&15)] ----
    #pragma unroll
    for (int r = 0; r < 4; ++r) {
        const float inv = (l_run[r] > 0.0f) ? 1.0f / l_run[r] : 0.0f;
        const size_t row = (size_t)(b * Ss + qt * 64 + w * 16 + (l >> 4) * 4 + r);
        #pragma unroll
        for (int jt = 0; jt < 4; ++jt)
            out[row * Hh + h * 64 + jt * 16 + (l & 15)] = f2bf(oa[jt][r] * inv);
    }
}

// ---------------------------------------------------------------------------
// Gate head: g[row] = sigmoid( h[row,0:512] . w2 + b2 ), fp32 in. 1 wave/row.
// ---------------------------------------------------------------------------
__global__ __launch_bounds__(256) void gate2_kernel(
    const float* __restrict__ h, const float* __restrict__ w2,
    const float* __restrict__ b2, float* __restrict__ outg, int R)
{
    const int wid = threadIdx.x / 64;
    const int lane = threadIdx.x % 64;
    const int row = blockIdx.x * 4 + wid;
    if (row >= R) return;
    const float* hr = h + (size_t)row * 512;
    float s = 0.0f;
    #pragma unroll
    for (int i = 0; i < 8; ++i) s += hr[lane + i * 64] * w2[lane + i * 64];
    #pragma unroll
    for (int o = 1; o < 64; o <<= 1) s += __shfl_xor(s, o);
    if (lane == 0) outg[row] = 1.0f / (1.0f + __expf(-(s + b2[0])));
}

// ---------------------------------------------------------------------------
// out = LayerNorm(hs + rg*retr_bf16) * g + b.  1 block / row.
// ---------------------------------------------------------------------------
__global__ __launch_bounds__(256) void out_ln_kernel(
    const float* __restrict__ hs, const unsigned short* __restrict__ retr,
    const float* __restrict__ rg, const float* __restrict__ gam,
    const float* __restrict__ bet, float* __restrict__ out)
{
    const int row = blockIdx.x;
    const int t = threadIdx.x;
    const float r = rg[row];
    float x[4];
    float s = 0.0f, s2 = 0.0f;
    #pragma unroll
    for (int i = 0; i < 4; ++i) {
        const int col = t + i * 256;
        const float val = hs[(size_t)row * Hh + col] +
                          r * bf2f(retr[(size_t)row * Hh + col]);
        x[i] = val; s += val; s2 += val * val;
    }
    #pragma unroll
    for (int o = 1; o < 64; o <<= 1) { s += __shfl_xor(s, o); s2 += __shfl_xor(s2, o); }
    __shared__ float rs[4], rs2[4];
    const int wid = t / 64, lane = t % 64;
    if (lane == 0) { rs[wid] = s; rs2[wid] = s2; }
    __syncthreads();
    const float tot = rs[0] + rs[1] + rs[2] + rs[3];
    const float tot2 = rs2[0] + rs2[1] + rs2[2] + rs2[3];
    const float mu = tot * (1.0f / Hh);
    const float var = tot2 * (1.0f / Hh) - mu * mu;
    const float rstd = rsqrtf(var + 1e-5f);
    #pragma unroll
    for (int i = 0; i < 4; ++i) {
        const int col = t + i * 256;
        out[(size_t)row * Hh + col] = (x[i] - mu) * rstd * gam[col] + bet[col];
    }
}

__global__ void wgmean_kernel(const float* __restrict__ wg_row,
                              float* __restrict__ wg_L)
{
    const int i = blockIdx.x * 256 + threadIdx.x;
    if (i < Bb * Ll)
        wg_L[i] = 0.25f * (wg_row[4 * i] + wg_row[4 * i + 1] +
                           wg_row[4 * i + 2] + wg_row[4 * i + 3]);
}

__global__ __launch_bounds__(256) void scatter_kernel(
    const float* __restrict__ comp, const float* __restrict__ wgL,
    const int* __restrict__ wp_ptr, float* __restrict__ bank_out)
{
    const int row = blockIdx.x;
    const int b = row / Ll, lx = row % Ll;
    const int wp = *wp_ptr;
    const int m = (wp + lx) % Mm;
    const float g = wgL[row];
    const int col = threadIdx.x * 4;
    float4 cv = *reinterpret_cast<const float4*>(comp + (size_t)row * Hh + col);
    cv.x *= g; cv.y *= g; cv.z *= g; cv.w *= g;
    *reinterpret_cast<float4*>(bank_out + ((size_t)(b * Mm + m)) * Hh + col) = cv;
}

__global__ void maskptr_kernel(const unsigned char* __restrict__ mask,
                               const int* __restrict__ wp_ptr,
                               float* __restrict__ mask_out,
                               float* __restrict__ ptr_out)
{
    const int i = blockIdx.x * 256 + threadIdx.x;
    const int wp = *wp_ptr;
    if (i < Bb * Mm) {
        const int m = i % Mm;
        int rel = m - (wp % Mm);
        if (rel < 0) rel += Mm;
        mask_out[i] = (mask[i] != 0 || rel < Ll) ? 1.0f : 0.0f;
    }
    if (i == 0) ptr_out[0] = (float)((wp + Ll) % Mm);
}

// ---------------------------------------------------------------------------
// Launch
// ---------------------------------------------------------------------------
extern "C" void kernel_launch(void* const* d_in, const int* in_sizes, int n_in,
                              void* d_out, int out_size, void* d_ws, size_t ws_size,
                              hipStream_t stream)
{
    const float* hs   = (const float*)d_in[0];
    const float* bank = (const float*)d_in[1];
    const unsigned char* mask = (const unsigned char*)d_in[2];
    const int*   wp   = (const int*)d_in[3];
    const float* Wc1 = (const float*)d_in[4];  const float* bc1 = (const float*)d_in[5];
    const float* Wc2 = (const float*)d_in[6];  const float* bc2 = (const float*)d_in[7];
    const float* Wq  = (const float*)d_in[8];  const float* bq  = (const float*)d_in[9];
    const float* Wk  = (const float*)d_in[10]; const float* bk  = (const float*)d_in[11];
    const float* Wv  = (const float*)d_in[12]; const float* bv  = (const float*)d_in[13];
    const float* Wo  = (const float*)d_in[14]; const float* bo  = (const float*)d_in[15];
    const float* Wwg1 = (const float*)d_in[16]; const float* bwg1 = (const float*)d_in[17];
    const float* Wwg2 = (const float*)d_in[18]; const float* bwg2 = (const float*)d_in[19];
    const float* Wrg1 = (const float*)d_in[20]; const float* brg1 = (const float*)d_in[21];
    const float* Wrg2 = (const float*)d_in[22]; const float* brg2 = (const float*)d_in[23];
    const float* ln_g = (const float*)d_in[24]; const float* ln_b = (const float*)d_in[25];

    float* out_main = (float*)d_out;                       // B*S*H
    float* out_bank = out_main + (size_t)Bb * Ss * Hh;     // B*M*H
    float* out_mask = out_bank + (size_t)Bb * Mm * Hh;     // B*M
    float* out_ptr  = out_mask + (size_t)Bb * Mm;          // 1

    // ---- workspace arena (bytes), top = 83,886,080 ----
    char* W = (char*)d_ws;
    unsigned short* hs_bf  = (unsigned short*)(W + 0);           // 16 MiB
    unsigned short* attslt = (unsigned short*)(W + 16777216);    // att_bf; later comp
    unsigned short* big1   = (unsigned short*)(W + 33554432);    // q_bf -> retr_bf
    unsigned short* wslot  = (unsigned short*)(W + 50331648);    // 8 MiB weight slot
    char*           big2   = W + 58720256;                       // 16 MiB
    char*           reg3   = W + 75497472;                       // 8 MiB

    unsigned short* att_bf  = attslt;
    unsigned short* q_bf    = big1;
    unsigned short* retr_bf = big1;
    unsigned short* k_bf    = (unsigned short*)(big2);
    unsigned short* v_bf    = (unsigned short*)(big2 + 8388608);
    unsigned short* bank_bf = (unsigned short*)(reg3);
    float* rg_h   = (float*)big2;            // after attn
    float* wg_h   = (float*)big2;            // after rg gate
    float* rg     = (float*)(reg3);          // after bank_bf dead
    float* wg_row = (float*)(reg3 + 32768);
    float* wg_L   = (float*)(reg3 + 65536);
    unsigned short* comp_h = attslt;                       // after Wo gemm
    float* comp   = (float*)((char*)attslt + 4194304);

    const int R = Bb * Ss;   // 8192

    // 0) casts
    cast_bf16_kernel<<<4096, 256, 0, stream>>>(hs, hs_bf, R * Hh / 8);
    cast_bf16_kernel<<<2048, 256, 0, stream>>>(bank, bank_bf, Bb * Mm * Hh / 8);

    // 1) Q,K,V projections (bf16 out)
    transpose_cast_kernel<<<dim3(32, 32), 256, 0, stream>>>(Wq, wslot, Hh, Hh);
    gemm_bf16_kernel<<<dim3(8, 64), 256, 0, stream>>>(
        hs_bf, hs_bf, Hh, wslot, bq, nullptr, q_bf, R, Hh, Hh, 0);
    transpose_cast_kernel<<<dim3(32, 32), 256, 0, stream>>>(Wk, wslot, Hh, Hh);
    gemm_bf16_kernel<<<dim3(8, 32), 256, 0, stream>>>(
        bank_bf, bank_bf, Hh, wslot, bk, nullptr, k_bf, Bb * Mm, Hh, Hh, 0);
    transpose_cast_kernel<<<dim3(32, 32), 256, 0, stream>>>(Wv, wslot, Hh, Hh);
    gemm_bf16_kernel<<<dim3(8, 32), 256, 0, stream>>>(
        bank_bf, bank_bf, Hh, wslot, bv, nullptr, v_bf, Bb * Mm, Hh, Hh, 0);

    // 2) attention -> att_bf
    attn_bf16_kernel<<<dim3(Ss / 64, NHh, Bb), 256, 0, stream>>>(
        q_bf, k_bf, v_bf, mask, att_bf);

    // 3) output projection -> retr_bf (overwrites q_bf slot)
    transpose_cast_kernel<<<dim3(32, 32), 256, 0, stream>>>(Wo, wslot, Hh, Hh);
    gemm_bf16_kernel<<<dim3(8, 64), 256, 0, stream>>>(
        att_bf, att_bf, Hh, wslot, bo, nullptr, retr_bf, R, Hh, Hh, 0);

    // 4) read gate
    transpose_cast_kernel<<<dim3(16, 64), 256, 0, stream>>>(Wrg1, wslot, 2 * Hh, 512);
    gemm_bf16_kernel<<<dim3(4, 64), 256, 0, stream>>>(
        hs_bf, retr_bf, Hh, wslot, brg1, rg_h, nullptr, R, 512, 2 * Hh, 1);
    gate2_kernel<<<R / 4, 256, 0, stream>>>(rg_h, Wrg2, brg2, rg, R);

    // 5) residual + layernorm -> out_main
    out_ln_kernel<<<R, 256, 0, stream>>>(hs, retr_bf, rg, ln_g, ln_b, out_main);

    // 6) write gate
    transpose_cast_kernel<<<dim3(16, 32), 256, 0, stream>>>(Wwg1, wslot, Hh, 512);
    gemm_bf16_kernel<<<dim3(4, 64), 256, 0, stream>>>(
        hs_bf, hs_bf, Hh, wslot, bwg1, wg_h, nullptr, R, 512, Hh, 1);
    gate2_kernel<<<R / 4, 256, 0, stream>>>(wg_h, Wwg2, bwg2, wg_row, R);
    wgmean_kernel<<<(Bb * Ll + 255) / 256, 256, 0, stream>>>(wg_row, wg_L);

    // 7) compressor (hs_bf viewed as [B*L][CR*H])
    transpose_cast_kernel<<<dim3(32, 128), 256, 0, stream>>>(Wc1, wslot, CRr * Hh, Hh);
    gemm_bf16_kernel<<<dim3(8, 16), 256, 0, stream>>>(
        hs_bf, hs_bf, CRr * Hh, wslot, bc1, nullptr, comp_h, Bb * Ll, Hh, CRr * Hh, 1);
    transpose_cast_kernel<<<dim3(32, 32), 256, 0, stream>>>(Wc2, wslot, Hh, Hh);
    gemm_bf16_kernel<<<dim3(8, 16), 256, 0, stream>>>(
        comp_h, comp_h, Hh, wslot, bc2, comp, nullptr, Bb * Ll, Hh, Hh, 0);

    // 8) new_bank = bank copy, then scatter gated compressed rows
    hipMemcpyAsync(out_bank, bank, (size_t)Bb * Mm * Hh * sizeof(float),
                   hipMemcpyDeviceToDevice, stream);
    scatter_kernel<<<Bb * Ll, 256, 0, stream>>>(comp, wg_L, wp, out_bank);

    // 9) mask + pointer
    maskptr_kernel<<<(Bb * Mm + 255) / 256, 256, 0, stream>>>(
        mask, wp, out_mask, out_ptr);
}

// Round 4
// 606.902 us; speedup vs baseline: 3.8063x; 1.0879x over previous
//
#include <hip/hip_runtime.h>
#include <hip/hip_bf16.h>

// Problem constants
#define Bb 4
#define Ss 2048
#define Hh 1024
#define Mm 1024
#define NHh 16
#define DHh 64
#define CRr 4
#define Ll (Ss / CRr)          // 512

typedef __attribute__((ext_vector_type(8))) short short8;    // 8 bf16
typedef __attribute__((ext_vector_type(4))) float f32x4;
typedef __attribute__((ext_vector_type(16))) float f32x16;

typedef __attribute__((address_space(1))) const unsigned int g_u32;
typedef __attribute__((address_space(3))) unsigned int l_u32;

__device__ inline void gload_lds16(const void* g, void* l) {
    __builtin_amdgcn_global_load_lds((g_u32*)g, (l_u32*)l, 16, 0, 0);
}

__device__ inline unsigned short f2bf(float x) {
    unsigned int u = __builtin_bit_cast(unsigned int, x);
    unsigned int r = u + 0x7FFFu + ((u >> 16) & 1u);   // RNE
    return (unsigned short)(r >> 16);
}
__device__ inline float bf2f(unsigned short u) {
    return __builtin_bit_cast(float, (unsigned int)u << 16);
}
__device__ inline unsigned int cvtpk_bf16(float lo, float hi2) {
    unsigned int r;
    asm("v_cvt_pk_bf16_f32 %0, %1, %2" : "=v"(r) : "v"(lo), "v"(hi2));
    return r;
}
__device__ inline f32x16 zero16() {
    f32x16 v;
    #pragma unroll
    for (int i = 0; i < 16; ++i) v[i] = 0.0f;
    return v;
}
// LDS fragment read with XOR chunk swizzle (rows are 128B; slot = 16B unit)
__device__ inline short8 lds_frag(const unsigned short* base, int row, int slot) {
    return *(const short8*)((const char*)base + row * 128 + ((slot ^ (row & 7)) << 4));
}

// ---------------------------------------------------------------------------
// f32 -> bf16 elementwise cast (8 elems / thread)
// ---------------------------------------------------------------------------
__global__ __launch_bounds__(256) void cast_bf16_kernel(
    const float* __restrict__ in, unsigned short* __restrict__ out, int n8)
{
    const int i = blockIdx.x * 256 + threadIdx.x;
    if (i >= n8) return;
    const float4* p = reinterpret_cast<const float4*>(in) + (size_t)i * 2;
    float4 a = p[0], b = p[1];
    uint4 o;
    o.x = (unsigned)f2bf(a.x) | ((unsigned)f2bf(a.y) << 16);
    o.y = (unsigned)f2bf(a.z) | ((unsigned)f2bf(a.w) << 16);
    o.z = (unsigned)f2bf(b.x) | ((unsigned)f2bf(b.y) << 16);
    o.w = (unsigned)f2bf(b.z) | ((unsigned)f2bf(b.w) << 16);
    *reinterpret_cast<uint4*>(out + (size_t)i * 8) = o;
}

// ---------------------------------------------------------------------------
// W[K][N] f32  ->  Wt[N][K] bf16  (transpose + cast), 32x32 tiles
// ---------------------------------------------------------------------------
__global__ __launch_bounds__(256) void transpose_cast_kernel(
    const float* __restrict__ W, unsigned short* __restrict__ Wt, int K, int N)
{
    __shared__ float tile[32][33];
    const int k0 = blockIdx.y * 32, n0 = blockIdx.x * 32;
    const int tx = threadIdx.x & 31, ty = threadIdx.x >> 5;   // ty 0..7
    #pragma unroll
    for (int r = 0; r < 32; r += 8)
        tile[r + ty][tx] = W[(size_t)(k0 + r + ty) * N + n0 + tx];
    __syncthreads();
    #pragma unroll
    for (int r = 0; r < 32; r += 8)
        Wt[(size_t)(n0 + r + ty) * K + k0 + tx] = f2bf(tile[tx][r + ty]);
}

// ---------------------------------------------------------------------------
// BF16 MFMA GEMM (NT): C = act( Acat[M][K] @ Wt[N][K]^T + bias )
//   Outputs: Cf (fp32) / Cb (bf16) / CbT (bf16, per-batch transposed
//   [b][col][key] with b=row>>10, key=row&1023 — used for V).
// ---------------------------------------------------------------------------
__global__ __launch_bounds__(256) void gemm_bf16_kernel(
    const unsigned short* __restrict__ A1, const unsigned short* __restrict__ A2,
    int K1, const unsigned short* __restrict__ Wt, const float* __restrict__ bias,
    float* __restrict__ Cf, unsigned short* __restrict__ Cb,
    unsigned short* __restrict__ CbT,
    int Mdim, int Ndim, int Kdim, int act)
{
    __shared__ __align__(16) unsigned short As[128 * 64];
    __shared__ __align__(16) unsigned short Bs[128 * 64];

    const int t = threadIdx.x;
    const int l = t & 63;
    const int w = t >> 6;
    const int bm = blockIdx.y * 128;
    const int bn = blockIdx.x * 128;
    const int m_off = (w >> 1) * 64;
    const int n_off = (w & 1) * 64;
    const int K2 = Kdim - K1;

    f32x4 acc[4][4];
    const f32x4 z = {0.f, 0.f, 0.f, 0.f};
    #pragma unroll
    for (int i = 0; i < 4; ++i)
        #pragma unroll
        for (int j = 0; j < 4; ++j) acc[i][j] = z;

    for (int kt = 0; kt < Kdim; kt += 64) {
        __syncthreads();
        const unsigned short* Ap; int rsA, kl;
        if (kt < K1) { Ap = A1; rsA = K1; kl = kt; }
        else         { Ap = A2; rsA = K2; kl = kt - K1; }
        #pragma unroll
        for (int i = 0; i < 4; ++i) {
            const int c = i * 256 + t;
            const int row = c >> 3;
            const int p = (c & 7) ^ (row & 7);
            gload_lds16(Ap + (size_t)(bm + row) * rsA + kl + p * 8,
                        (char*)As + c * 16);
            gload_lds16(Wt + (size_t)(bn + row) * Kdim + kt + p * 8,
                        (char*)Bs + c * 16);
        }
        __syncthreads();
        #pragma unroll
        for (int kk = 0; kk < 2; ++kk) {
            short8 af[4], bfr[4];
            #pragma unroll
            for (int i = 0; i < 4; ++i) {
                af[i]  = lds_frag(As, m_off + i * 16 + (l & 15), kk * 4 + (l >> 4));
                bfr[i] = lds_frag(Bs, n_off + i * 16 + (l & 15), kk * 4 + (l >> 4));
            }
            #pragma unroll
            for (int i = 0; i < 4; ++i)
                #pragma unroll
                for (int j = 0; j < 4; ++j)
                    acc[i][j] = __builtin_amdgcn_mfma_f32_16x16x32_bf16(
                        af[i], bfr[j], acc[i][j], 0, 0, 0);
        }
    }

    #pragma unroll
    for (int j = 0; j < 4; ++j) {
        const int col = bn + n_off + j * 16 + (l & 15);
        const float bj = bias[col];
        #pragma unroll
        for (int i = 0; i < 4; ++i) {
            if (CbT) {
                const int row0 = bm + m_off + i * 16 + (l >> 4) * 4;
                const int bidx = row0 >> 10, key = row0 & 1023;
                ushort4 pk4;
                float v0 = acc[i][j][0] + bj, v1 = acc[i][j][1] + bj;
                float v2 = acc[i][j][2] + bj, v3 = acc[i][j][3] + bj;
                pk4.x = f2bf(v0); pk4.y = f2bf(v1);
                pk4.z = f2bf(v2); pk4.w = f2bf(v3);
                *(ushort4*)(CbT + ((size_t)bidx << 20) + (size_t)col * 1024 + key) = pk4;
            } else {
                #pragma unroll
                for (int r = 0; r < 4; ++r) {
                    const int row = bm + m_off + i * 16 + (l >> 4) * 4 + r;
                    float v0 = acc[i][j][r] + bj;
                    if (act == 1) v0 = v0 / (1.0f + __expf(-v0));
                    if (Cf) Cf[(size_t)row * Ndim + col] = v0;
                    if (Cb) Cb[(size_t)row * Ndim + col] = f2bf(v0);
                }
            }
        }
    }
}

// ---------------------------------------------------------------------------
// Flash attention, swapped-QK^T in-register softmax, 32x32x16 MFMA.
// grid = (S/128, NH, B), 256 thr (4 waves, each owns 32 q-rows).
// q: [B*S][H] bf16; k: [B*M][H] bf16; vt: [B][H][M] bf16 (d-major).
// S^T = mfma(K,Q): lane&31 = q, regs = k.  O^T = mfma(V^T,P): lane&31 = q,
// regs = d.  Softmax entirely in registers (+1 shfl_xor(32) per reduce).
// ---------------------------------------------------------------------------
__global__ __launch_bounds__(256) void attn_mfma_kernel(
    const unsigned short* __restrict__ q, const unsigned short* __restrict__ k,
    const unsigned short* __restrict__ vt, const unsigned char* __restrict__ mask,
    unsigned short* __restrict__ out)
{
    const int qt = blockIdx.x, h = blockIdx.y, b = blockIdx.z;
    const int t = threadIdx.x, l = t & 63, w = t >> 6;
    const int lq = l & 31, hi = l >> 5;

    __shared__ __align__(16) unsigned short Ks[64 * 64];
    __shared__ __align__(16) unsigned short Vs[64 * 64];

    // Q fragments in registers (reused across all 16 chunks)
    short8 qf[4];
    {
        const int qg = qt * 128 + w * 32 + lq;
        const unsigned short* qp = q + ((size_t)(b * Ss + qg)) * Hh + h * 64 + hi * 8;
        #pragma unroll
        for (int tt = 0; tt < 4; ++tt) qf[tt] = *(const short8*)(qp + tt * 16);
    }

    f32x16 oacc0 = zero16(), oacc1 = zero16();
    float m_run = -3.0e38f, l_run = 0.0f;

    for (int c = 0; c < Mm / 64; ++c) {
        const int kc = c * 64;
        __syncthreads();
        // ---- stage K chunk [64 keys][64 d] and Vt chunk [64 d][64 keys],
        //      linear LDS dest + inverse-swizzled global source ----
        {
            const int c0 = t, c1 = t + 256;
            const int r0 = c0 >> 3, s0 = c0 & 7;
            const int r1 = c1 >> 3, s1 = c1 & 7;
            gload_lds16(k + ((size_t)(b * Mm + kc + r0)) * Hh + h * 64 + ((s0 ^ (r0 & 7)) * 8),
                        (char*)Ks + c0 * 16);
            gload_lds16(k + ((size_t)(b * Mm + kc + r1)) * Hh + h * 64 + ((s1 ^ (r1 & 7)) * 8),
                        (char*)Ks + c1 * 16);
            gload_lds16(vt + ((size_t)b << 20) + (size_t)(h * 64 + r0) * Mm + kc + ((s0 ^ (r0 & 7)) * 8),
                        (char*)Vs + c0 * 16);
            gload_lds16(vt + ((size_t)b << 20) + (size_t)(h * 64 + r1) * Mm + kc + ((s1 ^ (r1 & 7)) * 8),
                        (char*)Vs + c1 * 16);
        }
        __syncthreads();

        // ---- S^T: rows = key(regs), cols = q(lane) ----
        f32x16 st0 = zero16(), st1 = zero16();
        #pragma unroll
        for (int tt = 0; tt < 4; ++tt) {
            short8 k0 = lds_frag(Ks, lq,      2 * tt + hi);
            short8 k1 = lds_frag(Ks, 32 + lq, 2 * tt + hi);
            st0 = __builtin_amdgcn_mfma_f32_32x32x16_bf16(k0, qf[tt], st0, 0, 0, 0);
            st1 = __builtin_amdgcn_mfma_f32_32x32x16_bf16(k1, qf[tt], st1, 0, 0, 0);
        }

        // ---- mask + scale; krow = (r&3) + 8*(r>>2) + 4*hi + 32*kb ----
        float sv[32];
        #pragma unroll
        for (int kb = 0; kb < 2; ++kb) {
            const f32x16 stv = kb ? st1 : st0;
            #pragma unroll
            for (int g = 0; g < 4; ++g) {
                const unsigned int mu = *(const unsigned int*)
                    (mask + b * Mm + kc + kb * 32 + 8 * g + 4 * hi);
                #pragma unroll
                for (int j = 0; j < 4; ++j) {
                    const float s = stv[g * 4 + j] * 0.125f;
                    sv[kb * 16 + g * 4 + j] = ((mu >> (8 * j)) & 1) ? s : -3.0e38f;
                }
            }
        }

        // ---- online softmax, all in registers ----
        float mx = sv[0];
        #pragma unroll
        for (int i = 1; i < 32; ++i) mx = fmaxf(mx, sv[i]);
        mx = fmaxf(mx, __shfl_xor(mx, 32));
        const float m_new = fmaxf(m_run, mx);
        const float fac = __expf(m_run - m_new);
        m_run = m_new;

        float psum = 0.0f;
        #pragma unroll
        for (int i = 0; i < 32; ++i) {
            const float pv = (sv[i] > -1.0e37f) ? __expf(sv[i] - m_new) : 0.0f;
            sv[i] = pv; psum += pv;
        }
        psum += __shfl_xor(psum, 32);
        l_run = l_run * fac + psum;

        #pragma unroll
        for (int i = 0; i < 16; ++i) { oacc0[i] *= fac; oacc1[i] *= fac; }

        // ---- pack P into 4 MFMA fragments (k-steps of 16) ----
        short8 pf[4];
        #pragma unroll
        for (int kb = 0; kb < 2; ++kb) {
            #pragma unroll
            for (int gp = 0; gp < 2; ++gp) {
                const float* pp = &sv[kb * 16 + gp * 8];
                unsigned int u  = cvtpk_bf16(pp[0], pp[1]);   // (k0,k1)|(k4,k5)
                unsigned int v2 = cvtpk_bf16(pp[2], pp[3]);   // (k2,k3)|(k6,k7)
                unsigned int w2 = cvtpk_bf16(pp[4], pp[5]);   // (k8,k9)|(k12,k13)
                unsigned int z2 = cvtpk_bf16(pp[6], pp[7]);   // (k10,k11)|(k14,k15)
                unsigned int su = __shfl_xor(u, 32),  sv2 = __shfl_xor(v2, 32);
                unsigned int sw = __shfl_xor(w2, 32), sz  = __shfl_xor(z2, 32);
                const bool low = (hi == 0);
                union { unsigned int d[4]; short8 s; } fr;
                fr.d[0] = low ? u   : sw;
                fr.d[1] = low ? v2  : sz;
                fr.d[2] = low ? su  : w2;
                fr.d[3] = low ? sv2 : z2;
                pf[kb * 2 + gp] = fr.s;
            }
        }

        // ---- PV: O^T rows = d(regs), cols = q(lane) ----
        #pragma unroll
        for (int ks = 0; ks < 4; ++ks) {
            short8 v0 = lds_frag(Vs, lq,      2 * ks + hi);
            short8 v1 = lds_frag(Vs, 32 + lq, 2 * ks + hi);
            oacc0 = __builtin_amdgcn_mfma_f32_32x32x16_bf16(v0, pf[ks], oacc0, 0, 0, 0);
            oacc1 = __builtin_amdgcn_mfma_f32_32x32x16_bf16(v1, pf[ks], oacc1, 0, 0, 0);
        }
    }

    // ---- store O: lane owns q = lq; d = (r&3)+8*(r>>2)+4*hi+32*db ----
    const float inv = (l_run > 0.0f) ? 1.0f / l_run : 0.0f;
    const int qg = qt * 128 + w * 32 + lq;
    unsigned short* op = out + ((size_t)(b * Ss + qg)) * Hh + h * 64;
    #pragma unroll
    for (int db = 0; db < 2; ++db) {
        const f32x16 oa = db ? oacc1 : oacc0;
        #pragma unroll
        for (int g = 0; g < 4; ++g) {
            const int d0 = db * 32 + 8 * g + 4 * hi;
            ushort4 pk4;
            pk4.x = f2bf(oa[g * 4 + 0] * inv);
            pk4.y = f2bf(oa[g * 4 + 1] * inv);
            pk4.z = f2bf(oa[g * 4 + 2] * inv);
            pk4.w = f2bf(oa[g * 4 + 3] * inv);
            *(ushort4*)(op + d0) = pk4;
        }
    }
}

// ---------------------------------------------------------------------------
// Gate head: g[row] = sigmoid( h_bf16[row,0:512] . w2 + b2 ). 1 wave/row.
// ---------------------------------------------------------------------------
__global__ __launch_bounds__(256) void gate2_kernel(
    const unsigned short* __restrict__ h, const float* __restrict__ w2,
    const float* __restrict__ b2, float* __restrict__ outg, int R)
{
    const int wid = threadIdx.x / 64;
    const int lane = threadIdx.x % 64;
    const int row = blockIdx.x * 4 + wid;
    if (row >= R) return;
    short8 hv = *(const short8*)(h + (size_t)row * 512 + lane * 8);
    float4 w0 = *(const float4*)(w2 + lane * 8);
    float4 w1 = *(const float4*)(w2 + lane * 8 + 4);
    float s = bf2f((unsigned short)hv[0]) * w0.x + bf2f((unsigned short)hv[1]) * w0.y +
              bf2f((unsigned short)hv[2]) * w0.z + bf2f((unsigned short)hv[3]) * w0.w +
              bf2f((unsigned short)hv[4]) * w1.x + bf2f((unsigned short)hv[5]) * w1.y +
              bf2f((unsigned short)hv[6]) * w1.z + bf2f((unsigned short)hv[7]) * w1.w;
    #pragma unroll
    for (int o = 1; o < 64; o <<= 1) s += __shfl_xor(s, o);
    if (lane == 0) outg[row] = 1.0f / (1.0f + __expf(-(s + b2[0])));
}

// ---------------------------------------------------------------------------
// out = LayerNorm(hs + rg*retr_bf16) * g + b.  1 block / row.
// ---------------------------------------------------------------------------
__global__ __launch_bounds__(256) void out_ln_kernel(
    const float* __restrict__ hs, const unsigned short* __restrict__ retr,
    const float* __restrict__ rg, const float* __restrict__ gam,
    const float* __restrict__ bet, float* __restrict__ out)
{
    const int row = blockIdx.x;
    const int t = threadIdx.x;
    const float r = rg[row];
    float x[4];
    float s = 0.0f, s2 = 0.0f;
    #pragma unroll
    for (int i = 0; i < 4; ++i) {
        const int col = t + i * 256;
        const float val = hs[(size_t)row * Hh + col] +
                          r * bf2f(retr[(size_t)row * Hh + col]);
        x[i] = val; s += val; s2 += val * val;
    }
    #pragma unroll
    for (int o = 1; o < 64; o <<= 1) { s += __shfl_xor(s, o); s2 += __shfl_xor(s2, o); }
    __shared__ float rs[4], rs2[4];
    const int wid = t / 64, lane = t % 64;
    if (lane == 0) { rs[wid] = s; rs2[wid] = s2; }
    __syncthreads();
    const float tot = rs[0] + rs[1] + rs[2] + rs[3];
    const float tot2 = rs2[0] + rs2[1] + rs2[2] + rs2[3];
    const float mu = tot * (1.0f / Hh);
    const float var = tot2 * (1.0f / Hh) - mu * mu;
    const float rstd = rsqrtf(var + 1e-5f);
    #pragma unroll
    for (int i = 0; i < 4; ++i) {
        const int col = t + i * 256;
        out[(size_t)row * Hh + col] = (x[i] - mu) * rstd * gam[col] + bet[col];
    }
}

__global__ void wgmean_kernel(const float* __restrict__ wg_row,
                              float* __restrict__ wg_L)
{
    const int i = blockIdx.x * 256 + threadIdx.x;
    if (i < Bb * Ll)
        wg_L[i] = 0.25f * (wg_row[4 * i] + wg_row[4 * i + 1] +
                           wg_row[4 * i + 2] + wg_row[4 * i + 3]);
}

__global__ __launch_bounds__(256) void scatter_kernel(
    const float* __restrict__ comp, const float* __restrict__ wgL,
    const int* __restrict__ wp_ptr, float* __restrict__ bank_out)
{
    const int row = blockIdx.x;
    const int b = row / Ll, lx = row % Ll;
    const int wp = *wp_ptr;
    const int m = (wp + lx) % Mm;
    const float g = wgL[row];
    const int col = threadIdx.x * 4;
    float4 cv = *reinterpret_cast<const float4*>(comp + (size_t)row * Hh + col);
    cv.x *= g; cv.y *= g; cv.z *= g; cv.w *= g;
    *reinterpret_cast<float4*>(bank_out + ((size_t)(b * Mm + m)) * Hh + col) = cv;
}

__global__ void maskptr_kernel(const unsigned char* __restrict__ mask,
                               const int* __restrict__ wp_ptr,
                               float* __restrict__ mask_out,
                               float* __restrict__ ptr_out)
{
    const int i = blockIdx.x * 256 + threadIdx.x;
    const int wp = *wp_ptr;
    if (i < Bb * Mm) {
        const int m = i % Mm;
        int rel = m - (wp % Mm);
        if (rel < 0) rel += Mm;
        mask_out[i] = (mask[i] != 0 || rel < Ll) ? 1.0f : 0.0f;
    }
    if (i == 0) ptr_out[0] = (float)((wp + Ll) % Mm);
}

// ---------------------------------------------------------------------------
// Launch
// ---------------------------------------------------------------------------
extern "C" void kernel_launch(void* const* d_in, const int* in_sizes, int n_in,
                              void* d_out, int out_size, void* d_ws, size_t ws_size,
                              hipStream_t stream)
{
    const float* hs   = (const float*)d_in[0];
    const float* bank = (const float*)d_in[1];
    const unsigned char* mask = (const unsigned char*)d_in[2];
    const int*   wp   = (const int*)d_in[3];
    const float* Wc1 = (const float*)d_in[4];  const float* bc1 = (const float*)d_in[5];
    const float* Wc2 = (const float*)d_in[6];  const float* bc2 = (const float*)d_in[7];
    const float* Wq  = (const float*)d_in[8];  const float* bq  = (const float*)d_in[9];
    const float* Wk  = (const float*)d_in[10]; const float* bk  = (const float*)d_in[11];
    const float* Wv  = (const float*)d_in[12]; const float* bv  = (const float*)d_in[13];
    const float* Wo  = (const float*)d_in[14]; const float* bo  = (const float*)d_in[15];
    const float* Wwg1 = (const float*)d_in[16]; const float* bwg1 = (const float*)d_in[17];
    const float* Wwg2 = (const float*)d_in[18]; const float* bwg2 = (const float*)d_in[19];
    const float* Wrg1 = (const float*)d_in[20]; const float* brg1 = (const float*)d_in[21];
    const float* Wrg2 = (const float*)d_in[22]; const float* brg2 = (const float*)d_in[23];
    const float* ln_g = (const float*)d_in[24]; const float* ln_b = (const float*)d_in[25];

    float* out_main = (float*)d_out;                       // B*S*H
    float* out_bank = out_main + (size_t)Bb * Ss * Hh;     // B*M*H
    float* out_mask = out_bank + (size_t)Bb * Mm * Hh;     // B*M
    float* out_ptr  = out_mask + (size_t)Bb * Mm;          // 1

    // ---- workspace arena (bytes) ----
    char* W = (char*)d_ws;
    unsigned short* hs_bf  = (unsigned short*)(W + 0);           // 16 MiB
    unsigned short* attslt = (unsigned short*)(W + 16777216);    // att_bf; later comp
    unsigned short* big1   = (unsigned short*)(W + 33554432);    // q_bf -> retr_bf
    unsigned short* wslot  = (unsigned short*)(W + 50331648);    // 8 MiB weight slot
    char*           big2   = W + 58720256;                       // 16 MiB
    char*           reg3   = W + 75497472;                       // 8 MiB

    unsigned short* att_bf  = attslt;
    unsigned short* q_bf    = big1;
    unsigned short* retr_bf = big1;
    unsigned short* k_bf    = (unsigned short*)(big2);
    unsigned short* vt_bf   = (unsigned short*)(big2 + 8388608);  // [B][H][M]
    unsigned short* bank_bf = (unsigned short*)(reg3);
    unsigned short* rg_h    = (unsigned short*)big2;   // bf16 [R][512], after attn
    unsigned short* wg_h    = (unsigned short*)big2;   // bf16, after rg gate
    float* rg     = (float*)(reg3);                    // after bank_bf dead
    float* wg_row = (float*)(reg3 + 32768);
    float* wg_L   = (float*)(reg3 + 65536);
    unsigned short* comp_h = attslt;                   // after Wo gemm
    float* comp   = (float*)((char*)attslt + 4194304);

    const int R = Bb * Ss;   // 8192

    // 0) casts
    cast_bf16_kernel<<<4096, 256, 0, stream>>>(hs, hs_bf, R * Hh / 8);
    cast_bf16_kernel<<<2048, 256, 0, stream>>>(bank, bank_bf, Bb * Mm * Hh / 8);

    // 1) Q,K,V projections (V written transposed d-major)
    transpose_cast_kernel<<<dim3(32, 32), 256, 0, stream>>>(Wq, wslot, Hh, Hh);
    gemm_bf16_kernel<<<dim3(8, 64), 256, 0, stream>>>(
        hs_bf, hs_bf, Hh, wslot, bq, nullptr, q_bf, nullptr, R, Hh, Hh, 0);
    transpose_cast_kernel<<<dim3(32, 32), 256, 0, stream>>>(Wk, wslot, Hh, Hh);
    gemm_bf16_kernel<<<dim3(8, 32), 256, 0, stream>>>(
        bank_bf, bank_bf, Hh, wslot, bk, nullptr, k_bf, nullptr, Bb * Mm, Hh, Hh, 0);
    transpose_cast_kernel<<<dim3(32, 32), 256, 0, stream>>>(Wv, wslot, Hh, Hh);
    gemm_bf16_kernel<<<dim3(8, 32), 256, 0, stream>>>(
        bank_bf, bank_bf, Hh, wslot, bv, nullptr, nullptr, vt_bf, Bb * Mm, Hh, Hh, 0);

    // 2) attention -> att_bf
    attn_mfma_kernel<<<dim3(Ss / 128, NHh, Bb), 256, 0, stream>>>(
        q_bf, k_bf, vt_bf, mask, att_bf);

    // 3) output projection -> retr_bf (overwrites q_bf slot)
    transpose_cast_kernel<<<dim3(32, 32), 256, 0, stream>>>(Wo, wslot, Hh, Hh);
    gemm_bf16_kernel<<<dim3(8, 64), 256, 0, stream>>>(
        att_bf, att_bf, Hh, wslot, bo, nullptr, retr_bf, nullptr, R, Hh, Hh, 0);

    // 4) read gate (bf16 hidden)
    transpose_cast_kernel<<<dim3(16, 64), 256, 0, stream>>>(Wrg1, wslot, 2 * Hh, 512);
    gemm_bf16_kernel<<<dim3(4, 64), 256, 0, stream>>>(
        hs_bf, retr_bf, Hh, wslot, brg1, nullptr, rg_h, nullptr, R, 512, 2 * Hh, 1);
    gate2_kernel<<<R / 4, 256, 0, stream>>>(rg_h, Wrg2, brg2, rg, R);

    // 5) residual + layernorm -> out_main
    out_ln_kernel<<<R, 256, 0, stream>>>(hs, retr_bf, rg, ln_g, ln_b, out_main);

    // 6) write gate
    transpose_cast_kernel<<<dim3(16, 32), 256, 0, stream>>>(Wwg1, wslot, Hh, 512);
    gemm_bf16_kernel<<<dim3(4, 64), 256, 0, stream>>>(
        hs_bf, hs_bf, Hh, wslot, bwg1, nullptr, wg_h, nullptr, R, 512, Hh, 1);
    gate2_kernel<<<R / 4, 256, 0, stream>>>(wg_h, Wwg2, bwg2, wg_row, R);
    wgmean_kernel<<<(Bb * Ll + 255) / 256, 256, 0, stream>>>(wg_row, wg_L);

    // 7) compressor (hs_bf viewed as [B*L][CR*H])
    transpose_cast_kernel<<<dim3(32, 128), 256, 0, stream>>>(Wc1, wslot, CRr * Hh, Hh);
    gemm_bf16_kernel<<<dim3(8, 16), 256, 0, stream>>>(
        hs_bf, hs_bf, CRr * Hh, wslot, bc1, nullptr, comp_h, nullptr, Bb * Ll, Hh, CRr * Hh, 1);
    transpose_cast_kernel<<<dim3(32, 32), 256, 0, stream>>>(Wc2, wslot, Hh, Hh);
    gemm_bf16_kernel<<<dim3(8, 16), 256, 0, stream>>>(
        comp_h, comp_h, Hh, wslot, bc2, comp, nullptr, nullptr, Bb * Ll, Hh, Hh, 0);

    // 8) new_bank = bank copy, then scatter gated compressed rows
    hipMemcpyAsync(out_bank, bank, (size_t)Bb * Mm * Hh * sizeof(float),
                   hipMemcpyDeviceToDevice, stream);
    scatter_kernel<<<Bb * Ll, 256, 0, stream>>>(comp, wg_L, wp, out_bank);

    // 9) mask + pointer
    maskptr_kernel<<<(Bb * Mm + 255) / 256, 256, 0, stream>>>(
        mask, wp, out_mask, out_ptr);
}

// Round 7
// 530.412 us; speedup vs baseline: 4.3553x; 1.1442x over previous
//
#include <hip/hip_runtime.h>
#include <hip/hip_bf16.h>

// Problem constants
#define Bb 4
#define Ss 2048
#define Hh 1024
#define Mm 1024
#define NHh 16
#define DHh 64
#define CRr 4
#define Ll (Ss / CRr)          // 512

#define SC2 0.18033688f        // 0.125 * log2(e)

typedef __attribute__((ext_vector_type(8))) short short8;    // 8 bf16
typedef __attribute__((ext_vector_type(4))) float f32x4;
typedef __attribute__((ext_vector_type(16))) float f32x16;

typedef __attribute__((address_space(1))) const unsigned int g_u32;
typedef __attribute__((address_space(3))) unsigned int l_u32;

__device__ inline void gload_lds16(const void* g, void* l) {
    __builtin_amdgcn_global_load_lds((g_u32*)g, (l_u32*)l, 16, 0, 0);
}

__device__ inline unsigned short f2bf(float x) {
    unsigned int u = __builtin_bit_cast(unsigned int, x);
    unsigned int r = u + 0x7FFFu + ((u >> 16) & 1u);   // RNE
    return (unsigned short)(r >> 16);
}
__device__ inline float bf2f(unsigned short u) {
    return __builtin_bit_cast(float, (unsigned int)u << 16);
}
__device__ inline unsigned int cvtpk_bf16(float lo, float hi2) {
    unsigned int r;
    asm("v_cvt_pk_bf16_f32 %0, %1, %2" : "=v"(r) : "v"(lo), "v"(hi2));
    return r;
}
__device__ inline f32x16 zero16() {
    f32x16 v;
    #pragma unroll
    for (int i = 0; i < 16; ++i) v[i] = 0.0f;
    return v;
}
// LDS fragment read with XOR chunk swizzle (rows are 128B; slot = 16B unit)
__device__ inline short8 lds_frag(const unsigned short* base, int row, int slot) {
    return *(const short8*)((const char*)base + row * 128 + ((slot ^ (row & 7)) << 4));
}

// ---------------------------------------------------------------------------
// Fused f32 -> bf16 cast for hs and bank (8 elems / thread)
// ---------------------------------------------------------------------------
#define N8_HS  (Bb * Ss * Hh / 8)    // 1048576
#define N8_BK  (Bb * Mm * Hh / 8)    // 524288
__global__ __launch_bounds__(256) void cast2_kernel(
    const float* __restrict__ hs, const float* __restrict__ bank,
    unsigned short* __restrict__ hs_bf, unsigned short* __restrict__ bank_bf)
{
    int i = blockIdx.x * 256 + threadIdx.x;
    const float* src; unsigned short* dst;
    if (i < N8_HS) { src = hs; dst = hs_bf; }
    else           { src = bank; dst = bank_bf; i -= N8_HS; if (i >= N8_BK) return; }
    const float4* p = reinterpret_cast<const float4*>(src) + (size_t)i * 2;
    float4 a = p[0], b = p[1];
    uint4 o;
    o.x = (unsigned)f2bf(a.x) | ((unsigned)f2bf(a.y) << 16);
    o.y = (unsigned)f2bf(a.z) | ((unsigned)f2bf(a.w) << 16);
    o.z = (unsigned)f2bf(b.x) | ((unsigned)f2bf(b.y) << 16);
    o.w = (unsigned)f2bf(b.z) | ((unsigned)f2bf(b.w) << 16);
    *reinterpret_cast<uint4*>(dst + (size_t)i * 8) = o;
}

// ---------------------------------------------------------------------------
// All weight transposes in ONE kernel: W[K][N] f32 -> Wt[N][K] bf16.
// Job table hardcoded; grid = 10752 tiles of 32x32.
// ---------------------------------------------------------------------------
__global__ __launch_bounds__(256) void transpose_all_kernel(
    const float* __restrict__ Wq, const float* __restrict__ Wwg1,
    const float* __restrict__ Wk, const float* __restrict__ Wv,
    const float* __restrict__ Wo, const float* __restrict__ Wrg1,
    const float* __restrict__ Wc1, const float* __restrict__ Wc2,
    unsigned short* wtQW, unsigned short* wtKV, unsigned short* wtO,
    unsigned short* wtRG, unsigned short* wtC1, unsigned short* wtC2)
{
    int bid = blockIdx.x;
    const float* src; unsigned short* dst; int K, N;
    if (bid < 1024)      { src = Wq;   dst = wtQW;              K = 1024; N = 1024; }
    else if (bid < 1536) { src = Wwg1; dst = wtQW + 1048576;    K = 1024; N = 512;  bid -= 1024; }
    else if (bid < 2560) { src = Wk;   dst = wtKV;              K = 1024; N = 1024; bid -= 1536; }
    else if (bid < 3584) { src = Wv;   dst = wtKV + 1048576;    K = 1024; N = 1024; bid -= 2560; }
    else if (bid < 4608) { src = Wo;   dst = wtO;               K = 1024; N = 1024; bid -= 3584; }
    else if (bid < 5632) { src = Wrg1; dst = wtRG;              K = 2048; N = 512;  bid -= 4608; }
    else if (bid < 9728) { src = Wc1;  dst = wtC1;              K = 4096; N = 1024; bid -= 5632; }
    else                 { src = Wc2;  dst = wtC2;              K = 1024; N = 1024; bid -= 9728; }
    const int ntx = N >> 5;
    const int k0 = (bid / ntx) * 32, n0 = (bid % ntx) * 32;

    __shared__ float tile[32][33];
    const int tx = threadIdx.x & 31, ty = threadIdx.x >> 5;
    #pragma unroll
    for (int r = 0; r < 32; r += 8)
        tile[r + ty][tx] = src[(size_t)(k0 + r + ty) * N + n0 + tx];
    __syncthreads();
    #pragma unroll
    for (int r = 0; r < 32; r += 8)
        dst[(size_t)(n0 + r + ty) * K + k0 + tx] = f2bf(tile[tx][r + ty]);
}

// ---------------------------------------------------------------------------
// mask -> additive bias (exp2 domain): 0 if unmasked, -1e30 if masked
// ---------------------------------------------------------------------------
__global__ void maskbias_kernel(const unsigned char* __restrict__ mask,
                                float* __restrict__ bias_arr)
{
    const int i = blockIdx.x * 256 + threadIdx.x;
    if (i < Bb * Mm) bias_arr[i] = mask[i] ? 0.0f : -1.0e30f;
}

// ---------------------------------------------------------------------------
// BF16 MFMA GEMM (NT), dual output regions split at column N1.
// modes: 0=bf16, 1=bf16+SiLU, 2=bf16 transposed [b][d][key] (V),
//        3=f32 gated circular-scatter into bank (c2).
// XCD-swizzled grid (T1).
// ---------------------------------------------------------------------------
#define GM_BF16  0
#define GM_BF16S 1
#define GM_BF16T 2
#define GM_F32G  3

__global__ __launch_bounds__(256) void gemm_bf16_kernel(
    const unsigned short* __restrict__ A1, const unsigned short* __restrict__ A2,
    int K1, const unsigned short* __restrict__ Wt,
    const float* __restrict__ bias1, const float* __restrict__ bias2, int N1,
    void* out1, void* out2, int mode1, int mode2,
    int Mdim, int Ntot, int Kdim,
    const int* __restrict__ wp_ptr, const float* __restrict__ wg_row)
{
    __shared__ __align__(16) unsigned short As[128 * 64];
    __shared__ __align__(16) unsigned short Bs[128 * 64];

    const int t = threadIdx.x;
    const int l = t & 63;
    const int w = t >> 6;

    // XCD-aware swizzle (all grids have nwg % 8 == 0)
    const int nx = gridDim.x;
    const int nwg = nx * gridDim.y;
    const int bid0 = blockIdx.y * nx + blockIdx.x;
    const int swz = (nwg & 7) ? bid0 : ((bid0 & 7) * (nwg >> 3) + (bid0 >> 3));
    const int bm = (swz / nx) * 128;
    const int bn = (swz % nx) * 128;

    const int m_off = (w >> 1) * 64;
    const int n_off = (w & 1) * 64;
    const int K2 = Kdim - K1;

    f32x4 acc[4][4];
    const f32x4 z = {0.f, 0.f, 0.f, 0.f};
    #pragma unroll
    for (int i = 0; i < 4; ++i)
        #pragma unroll
        for (int j = 0; j < 4; ++j) acc[i][j] = z;

    for (int kt = 0; kt < Kdim; kt += 64) {
        __syncthreads();
        const unsigned short* Ap; int rsA, kl;
        if (kt < K1) { Ap = A1; rsA = K1; kl = kt; }
        else         { Ap = A2; rsA = K2; kl = kt - K1; }
        #pragma unroll
        for (int i = 0; i < 4; ++i) {
            const int c = i * 256 + t;
            const int row = c >> 3;
            const int p = (c & 7) ^ (row & 7);
            gload_lds16(Ap + (size_t)(bm + row) * rsA + kl + p * 8,
                        (char*)As + c * 16);
            gload_lds16(Wt + (size_t)(bn + row) * Kdim + kt + p * 8,
                        (char*)Bs + c * 16);
        }
        __syncthreads();
        #pragma unroll
        for (int kk = 0; kk < 2; ++kk) {
            short8 af[4], bfr[4];
            #pragma unroll
            for (int i = 0; i < 4; ++i) {
                af[i]  = lds_frag(As, m_off + i * 16 + (l & 15), kk * 4 + (l >> 4));
                bfr[i] = lds_frag(Bs, n_off + i * 16 + (l & 15), kk * 4 + (l >> 4));
            }
            #pragma unroll
            for (int i = 0; i < 4; ++i)
                #pragma unroll
                for (int j = 0; j < 4; ++j)
                    acc[i][j] = __builtin_amdgcn_mfma_f32_16x16x32_bf16(
                        af[i], bfr[j], acc[i][j], 0, 0, 0);
        }
    }

    // gated-scatter precompute (c2 only)
    float gg[16]; int wpv = 0;
    if (mode1 == GM_F32G) {
        wpv = *wp_ptr;
        #pragma unroll
        for (int i = 0; i < 4; ++i)
            #pragma unroll
            for (int r = 0; r < 4; ++r) {
                const int row = bm + m_off + i * 16 + (l >> 4) * 4 + r;
                gg[i * 4 + r] = 0.25f * (wg_row[4 * row] + wg_row[4 * row + 1] +
                                         wg_row[4 * row + 2] + wg_row[4 * row + 3]);
            }
    }

    #pragma unroll
    for (int j = 0; j < 4; ++j) {
        const int col = bn + n_off + j * 16 + (l & 15);
        const bool sec = (col >= N1);                 // uniform per j (N1 % 16 == 0)
        const int cl = sec ? col - N1 : col;
        const int mode = sec ? mode2 : mode1;
        const float bj = sec ? bias2[cl] : bias1[cl];
        const int nd = sec ? (Ntot - N1) : N1;
        if (mode == GM_BF16T) {
            unsigned short* ob = (unsigned short*)out2;
            #pragma unroll
            for (int i = 0; i < 4; ++i) {
                const int row0 = bm + m_off + i * 16 + (l >> 4) * 4;
                const int bidx = row0 >> 10, key = row0 & 1023;
                ushort4 pk4;
                pk4.x = f2bf(acc[i][j][0] + bj);
                pk4.y = f2bf(acc[i][j][1] + bj);
                pk4.z = f2bf(acc[i][j][2] + bj);
                pk4.w = f2bf(acc[i][j][3] + bj);
                *(ushort4*)(ob + ((size_t)bidx << 20) + (size_t)cl * 1024 + key) = pk4;
            }
        } else if (mode == GM_F32G) {
            float* ob = (float*)out1;
            #pragma unroll
            for (int i = 0; i < 4; ++i)
                #pragma unroll
                for (int r = 0; r < 4; ++r) {
                    const int row = bm + m_off + i * 16 + (l >> 4) * 4 + r;
                    const int bb = row >> 9, lx = row & 511;
                    const int m = (wpv + lx) & 1023;
                    ob[((size_t)(bb * 1024 + m)) * 1024 + col] =
                        (acc[i][j][r] + bj) * gg[i * 4 + r];
                }
        } else {
            unsigned short* ob = (unsigned short*)(sec ? out2 : out1);
            #pragma unroll
            for (int i = 0; i < 4; ++i)
                #pragma unroll
                for (int r = 0; r < 4; ++r) {
                    const int row = bm + m_off + i * 16 + (l >> 4) * 4 + r;
                    float v0 = acc[i][j][r] + bj;
                    if (mode == GM_BF16S) v0 = v0 / (1.0f + __expf(-v0));
                    ob[(size_t)row * nd + cl] = f2bf(v0);
                }
        }
    }
}

// ---------------------------------------------------------------------------
// Flash attention, swapped-QK^T in-register softmax, exp2 domain, defer-max.
// grid = (S/128, NH, B), 256 thr (4 waves x 32 q-rows).
// ---------------------------------------------------------------------------
__global__ __launch_bounds__(256) void attn_mfma_kernel(
    const unsigned short* __restrict__ q, const unsigned short* __restrict__ k,
    const unsigned short* __restrict__ vt, const float* __restrict__ bias_arr,
    unsigned short* __restrict__ out)
{
    const int qt = blockIdx.x, h = blockIdx.y, b = blockIdx.z;
    const int t = threadIdx.x, l = t & 63, w = t >> 6;
    const int lq = l & 31, hi = l >> 5;

    __shared__ __align__(16) unsigned short Ks[64 * 64];
    __shared__ __align__(16) unsigned short Vs[64 * 64];

    short8 qf[4];
    {
        const int qg = qt * 128 + w * 32 + lq;
        const unsigned short* qp = q + ((size_t)(b * Ss + qg)) * Hh + h * 64 + hi * 8;
        #pragma unroll
        for (int tt = 0; tt < 4; ++tt) qf[tt] = *(const short8*)(qp + tt * 16);
    }

    f32x16 oacc0 = zero16(), oacc1 = zero16();
    float m_run = -1.0e38f, l_run = 0.0f;

    for (int c = 0; c < Mm / 64; ++c) {
        const int kc = c * 64;
        __syncthreads();
        {
            const int c0 = t, c1 = t + 256;
            const int r0 = c0 >> 3, s0 = c0 & 7;
            const int r1 = c1 >> 3, s1 = c1 & 7;
            gload_lds16(k + ((size_t)(b * Mm + kc + r0)) * Hh + h * 64 + ((s0 ^ (r0 & 7)) * 8),
                        (char*)Ks + c0 * 16);
            gload_lds16(k + ((size_t)(b * Mm + kc + r1)) * Hh + h * 64 + ((s1 ^ (r1 & 7)) * 8),
                        (char*)Ks + c1 * 16);
            gload_lds16(vt + ((size_t)b << 20) + (size_t)(h * 64 + r0) * Mm + kc + ((s0 ^ (r0 & 7)) * 8),
                        (char*)Vs + c0 * 16);
            gload_lds16(vt + ((size_t)b << 20) + (size_t)(h * 64 + r1) * Mm + kc + ((s1 ^ (r1 & 7)) * 8),
                        (char*)Vs + c1 * 16);
        }
        __syncthreads();

        // ---- S^T = K . Q ----
        f32x16 st0 = zero16(), st1 = zero16();
        #pragma unroll
        for (int tt = 0; tt < 4; ++tt) {
            short8 k0 = lds_frag(Ks, lq,      2 * tt + hi);
            short8 k1 = lds_frag(Ks, 32 + lq, 2 * tt + hi);
            st0 = __builtin_amdgcn_mfma_f32_32x32x16_bf16(k0, qf[tt], st0, 0, 0, 0);
            st1 = __builtin_amdgcn_mfma_f32_32x32x16_bf16(k1, qf[tt], st1, 0, 0, 0);
        }

        // ---- scale to exp2 domain + additive mask bias (one fma each) ----
        float sv[32];
        #pragma unroll
        for (int kb = 0; kb < 2; ++kb) {
            const f32x16 stv = kb ? st1 : st0;
            #pragma unroll
            for (int g = 0; g < 4; ++g) {
                const float4 bf4 = *(const float4*)
                    (bias_arr + b * Mm + kc + kb * 32 + 8 * g + 4 * hi);
                sv[kb * 16 + g * 4 + 0] = fmaf(stv[g * 4 + 0], SC2, bf4.x);
                sv[kb * 16 + g * 4 + 1] = fmaf(stv[g * 4 + 1], SC2, bf4.y);
                sv[kb * 16 + g * 4 + 2] = fmaf(stv[g * 4 + 2], SC2, bf4.z);
                sv[kb * 16 + g * 4 + 3] = fmaf(stv[g * 4 + 3], SC2, bf4.w);
            }
        }

        // ---- max (tree) + cross-half ----
        float mx = fmaxf(sv[0], fmaxf(sv[1], sv[2]));
        #pragma unroll
        for (int i = 3; i < 31; i += 2) mx = fmaxf(mx, fmaxf(sv[i], sv[i + 1]));
        mx = fmaxf(mx, sv[31]);
        mx = fmaxf(mx, __shfl_xor(mx, 32));

        // ---- defer-max: rescale only when the max actually grows ----
        if (!__all(mx <= m_run + 10.0f)) {
            const float m_new = fmaxf(m_run, mx);
            const float fac = exp2f(m_run - m_new);
            m_run = m_new;
            l_run *= fac;
            #pragma unroll
            for (int i = 0; i < 16; ++i) { oacc0[i] *= fac; oacc1[i] *= fac; }
        }

        // ---- P = exp2(s - m), sum ----
        float psum = 0.0f;
        #pragma unroll
        for (int i = 0; i < 32; ++i) {
            const float pv = exp2f(sv[i] - m_run);
            sv[i] = pv; psum += pv;
        }
        psum += __shfl_xor(psum, 32);
        l_run += psum;

        // ---- pack P into 4 MFMA fragments ----
        short8 pf[4];
        #pragma unroll
        for (int kb = 0; kb < 2; ++kb) {
            #pragma unroll
            for (int gp = 0; gp < 2; ++gp) {
                const float* pp = &sv[kb * 16 + gp * 8];
                unsigned int u  = cvtpk_bf16(pp[0], pp[1]);
                unsigned int v2 = cvtpk_bf16(pp[2], pp[3]);
                unsigned int w2 = cvtpk_bf16(pp[4], pp[5]);
                unsigned int z2 = cvtpk_bf16(pp[6], pp[7]);
                unsigned int su = __shfl_xor(u, 32),  sv2 = __shfl_xor(v2, 32);
                unsigned int sw = __shfl_xor(w2, 32), sz  = __shfl_xor(z2, 32);
                const bool low = (hi == 0);
                union { unsigned int d[4]; short8 s; } fr;
                fr.d[0] = low ? u   : sw;
                fr.d[1] = low ? v2  : sz;
                fr.d[2] = low ? su  : w2;
                fr.d[3] = low ? sv2 : z2;
                pf[kb * 2 + gp] = fr.s;
            }
        }

        // ---- PV: O^T = V^T . P ----
        #pragma unroll
        for (int ks = 0; ks < 4; ++ks) {
            short8 v0 = lds_frag(Vs, lq,      2 * ks + hi);
            short8 v1 = lds_frag(Vs, 32 + lq, 2 * ks + hi);
            oacc0 = __builtin_amdgcn_mfma_f32_32x32x16_bf16(v0, pf[ks], oacc0, 0, 0, 0);
            oacc1 = __builtin_amdgcn_mfma_f32_32x32x16_bf16(v1, pf[ks], oacc1, 0, 0, 0);
        }
    }

    const float inv = (l_run > 0.0f) ? 1.0f / l_run : 0.0f;
    const int qg = qt * 128 + w * 32 + lq;
    unsigned short* op = out + ((size_t)(b * Ss + qg)) * Hh + h * 64;
    #pragma unroll
    for (int db = 0; db < 2; ++db) {
        const f32x16 oa = db ? oacc1 : oacc0;
        #pragma unroll
        for (int g = 0; g < 4; ++g) {
            const int d0 = db * 32 + 8 * g + 4 * hi;
            ushort4 pk4;
            pk4.x = f2bf(oa[g * 4 + 0] * inv);
            pk4.y = f2bf(oa[g * 4 + 1] * inv);
            pk4.z = f2bf(oa[g * 4 + 2] * inv);
            pk4.w = f2bf(oa[g * 4 + 3] * inv);
            *(ushort4*)(op + d0) = pk4;
        }
    }
}

// ---------------------------------------------------------------------------
// Gate head (write gate): g[row] = sigmoid( wg_h[row,0:512] . w2 + b2 )
// ---------------------------------------------------------------------------
__global__ __launch_bounds__(256) void gate2_kernel(
    const unsigned short* __restrict__ h, const float* __restrict__ w2,
    const float* __restrict__ b2, float* __restrict__ outg, int R)
{
    const int wid = threadIdx.x / 64;
    const int lane = threadIdx.x % 64;
    const int row = blockIdx.x * 4 + wid;
    if (row >= R) return;
    short8 hv = *(const short8*)(h + (size_t)row * 512 + lane * 8);
    float4 w0 = *(const float4*)(w2 + lane * 8);
    float4 w1 = *(const float4*)(w2 + lane * 8 + 4);
    float s = bf2f((unsigned short)hv[0]) * w0.x + bf2f((unsigned short)hv[1]) * w0.y +
              bf2f((unsigned short)hv[2]) * w0.z + bf2f((unsigned short)hv[3]) * w0.w +
              bf2f((unsigned short)hv[4]) * w1.x + bf2f((unsigned short)hv[5]) * w1.y +
              bf2f((unsigned short)hv[6]) * w1.z + bf2f((unsigned short)hv[7]) * w1.w;
    #pragma unroll
    for (int o = 1; o < 64; o <<= 1) s += __shfl_xor(s, o);
    if (lane == 0) outg[row] = 1.0f / (1.0f + __expf(-(s + b2[0])));
}

// ---------------------------------------------------------------------------
// out = LayerNorm(hs + rg*retr) with rg computed in-kernel from rg_h.
// 1 block (256 thr) per row.
// ---------------------------------------------------------------------------
__global__ __launch_bounds__(256) void out_ln_kernel(
    const float* __restrict__ hs, const unsigned short* __restrict__ retr,
    const unsigned short* __restrict__ rg_h, const float* __restrict__ Wrg2,
    const float* __restrict__ brg2, const float* __restrict__ gam,
    const float* __restrict__ bet, float* __restrict__ out)
{
    const int row = blockIdx.x;
    const int t = threadIdx.x;
    const int wid = t >> 6, lane = t & 63;

    // ---- read-gate dot: rg_h[row][0:512] . Wrg2 ----
    const unsigned int hv = *(const unsigned int*)(rg_h + (size_t)row * 512 + t * 2);
    const float2 wv = *(const float2*)(Wrg2 + t * 2);
    float sd = bf2f((unsigned short)(hv & 0xffffu)) * wv.x +
               bf2f((unsigned short)(hv >> 16)) * wv.y;
    #pragma unroll
    for (int o = 1; o < 64; o <<= 1) sd += __shfl_xor(sd, o);
    __shared__ float rsd[4];
    if (lane == 0) rsd[wid] = sd;
    __syncthreads();
    const float r = 1.0f / (1.0f + __expf(-(rsd[0] + rsd[1] + rsd[2] + rsd[3] + brg2[0])));

    // ---- residual + LN ----
    float x[4];
    float s = 0.0f, s2 = 0.0f;
    #pragma unroll
    for (int i = 0; i < 4; ++i) {
        const int col = t + i * 256;
        const float val = hs[(size_t)row * Hh + col] +
                          r * bf2f(retr[(size_t)row * Hh + col]);
        x[i] = val; s += val; s2 += val * val;
    }
    #pragma unroll
    for (int o = 1; o < 64; o <<= 1) { s += __shfl_xor(s, o); s2 += __shfl_xor(s2, o); }
    __shared__ float rs[4], rs2[4];
    if (lane == 0) { rs[wid] = s; rs2[wid] = s2; }
    __syncthreads();
    const float tot = rs[0] + rs[1] + rs[2] + rs[3];
    const float tot2 = rs2[0] + rs2[1] + rs2[2] + rs2[3];
    const float mu = tot * (1.0f / Hh);
    const float var = tot2 * (1.0f / Hh) - mu * mu;
    const float rstd = rsqrtf(var + 1e-5f);
    #pragma unroll
    for (int i = 0; i < 4; ++i) {
        const int col = t + i * 256;
        out[(size_t)row * Hh + col] = (x[i] - mu) * rstd * gam[col] + bet[col];
    }
}

// ---------------------------------------------------------------------------
// Copy unwritten bank rows + emit new_mask and new_ptr.
// ---------------------------------------------------------------------------
__global__ __launch_bounds__(256) void bankfix_kernel(
    const float* __restrict__ bank, const unsigned char* __restrict__ mask,
    const int* __restrict__ wp_ptr, float* __restrict__ out_bank,
    float* __restrict__ out_mask, float* __restrict__ out_ptr)
{
    const int row = blockIdx.x;          // b*M + m
    const int wp = *wp_ptr;
    const int m = row & 1023;
    int rel = m - (wp & 1023);
    if (rel < 0) rel += Mm;
    const bool written = rel < Ll;
    if (!written) {
        const int col = threadIdx.x * 4;
        *(float4*)(out_bank + (size_t)row * Hh + col) =
            *(const float4*)(bank + (size_t)row * Hh + col);
    }
    if (threadIdx.x == 0) out_mask[row] = (mask[row] != 0 || written) ? 1.0f : 0.0f;
    if (row == 0 && threadIdx.x == 0) out_ptr[0] = (float)((wp + Ll) % Mm);
}

// ---------------------------------------------------------------------------
// Launch
// ---------------------------------------------------------------------------
extern "C" void kernel_launch(void* const* d_in, const int* in_sizes, int n_in,
                              void* d_out, int out_size, void* d_ws, size_t ws_size,
                              hipStream_t stream)
{
    const float* hs   = (const float*)d_in[0];
    const float* bank = (const float*)d_in[1];
    const unsigned char* mask = (const unsigned char*)d_in[2];
    const int*   wp   = (const int*)d_in[3];
    const float* Wc1 = (const float*)d_in[4];  const float* bc1 = (const float*)d_in[5];
    const float* Wc2 = (const float*)d_in[6];  const float* bc2 = (const float*)d_in[7];
    const float* Wq  = (const float*)d_in[8];  const float* bq  = (const float*)d_in[9];
    const float* Wk  = (const float*)d_in[10]; const float* bk  = (const float*)d_in[11];
    const float* Wv  = (const float*)d_in[12]; const float* bv  = (const float*)d_in[13];
    const float* Wo  = (const float*)d_in[14]; const float* bo  = (const float*)d_in[15];
    const float* Wwg1 = (const float*)d_in[16]; const float* bwg1 = (const float*)d_in[17];
    const float* Wwg2 = (const float*)d_in[18]; const float* bwg2 = (const float*)d_in[19];
    const float* Wrg1 = (const float*)d_in[20]; const float* brg1 = (const float*)d_in[21];
    const float* Wrg2 = (const float*)d_in[22]; const float* brg2 = (const float*)d_in[23];
    const float* ln_g = (const float*)d_in[24]; const float* ln_b = (const float*)d_in[25];

    float* out_main = (float*)d_out;                       // B*S*H floats (32 MiB)
    float* out_bank = out_main + (size_t)Bb * Ss * Hh;     // B*M*H floats (16 MiB)
    float* out_mask = out_bank + (size_t)Bb * Mm * Hh;     // B*M
    float* out_ptr  = out_mask + (size_t)Bb * Mm;          // 1

    // ---- d_out as scratch (all dead before the final writes) ----
    // out_main (32 MiB): q_bf 16 MiB | att_bf 16 MiB
    unsigned short* q_bf   = (unsigned short*)out_main;
    unsigned short* att_bf = (unsigned short*)out_main + 8388608;
    // out_bank (16 MiB, in shorts): wtQW 3M | wtO 2M | wtRG 2M | wtC1 8M = 15 MiB ✓
    unsigned short* wtQW = (unsigned short*)out_bank;                // 1,572,864 sh
    unsigned short* wtO  = (unsigned short*)out_bank + 1572864;      // 1,048,576 sh
    unsigned short* wtRG = (unsigned short*)out_bank + 2621440;      // 1,048,576 sh
    unsigned short* wtC1 = (unsigned short*)out_bank + 3670016;      // 4,194,304 sh -> ends 7,864,320 < 8,388,608 ✓

    // ---- workspace arena (proven >= 80 MiB; top usage 73.5 MB) ----
    char* W = (char*)d_ws;
    unsigned short* hs_bf   = (unsigned short*)(W + 0);          // 16 MiB
    unsigned short* bank_bf = (unsigned short*)(W + 16777216);   // 8 MiB (dead after KV)
    unsigned short* rg_h    = (unsigned short*)(W + 16777216);   // reuse (8 MiB)
    unsigned short* retr_bf = (unsigned short*)(W + 25165824);   // 16 MiB
    unsigned short* k_bf    = (unsigned short*)(W + 41943040);   // 8 MiB
    unsigned short* vt_bf   = (unsigned short*)(W + 50331648);   // 8 MiB (dead after attn)
    unsigned short* comp_h  = (unsigned short*)(W + 50331648);   // reuse (4 MiB)
    unsigned short* wg_h    = (unsigned short*)(W + 58720256);   // 8 MiB
    unsigned short* wtC2    = (unsigned short*)(W + 67108864);   // 2 MiB -> 69,206,016
    unsigned short* wtKV    = (unsigned short*)(W + 69206016);   // 4 MiB -> 73,400,320
    float* wg_row   = (float*)(W + 73400320);                    // 32 KiB -> 73,433,088
    float* bias_arr = (float*)(W + 73433088);                    // 16 KiB -> 73,449,472

    // 1) casts
    cast2_kernel<<<(N8_HS + N8_BK + 255) / 256, 256, 0, stream>>>(
        hs, bank, hs_bf, bank_bf);

    // 2) all weight transposes
    transpose_all_kernel<<<10752, 256, 0, stream>>>(
        Wq, Wwg1, Wk, Wv, Wo, Wrg1, Wc1, Wc2,
        wtQW, wtKV, wtO, wtRG, wtC1, wtC2);

    // 3) mask bias
    maskbias_kernel<<<16, 256, 0, stream>>>(mask, bias_arr);

    // 4) fused Q + write-gate hidden   [8192 x 1536]
    gemm_bf16_kernel<<<dim3(12, 64), 256, 0, stream>>>(
        hs_bf, hs_bf, Hh, wtQW, bq, bwg1, 1024,
        q_bf, wg_h, GM_BF16, GM_BF16S, Bb * Ss, 1536, Hh, nullptr, nullptr);

    // 5) fused K + V (V transposed)    [4096 x 2048]
    gemm_bf16_kernel<<<dim3(16, 32), 256, 0, stream>>>(
        bank_bf, bank_bf, Hh, wtKV, bk, bv, 1024,
        k_bf, vt_bf, GM_BF16, GM_BF16T, Bb * Mm, 2048, Hh, nullptr, nullptr);

    // 6) attention
    attn_mfma_kernel<<<dim3(Ss / 128, NHh, Bb), 256, 0, stream>>>(
        q_bf, k_bf, vt_bf, bias_arr, att_bf);

    // 7) output projection
    gemm_bf16_kernel<<<dim3(8, 64), 256, 0, stream>>>(
        att_bf, att_bf, Hh, wtO, bo, bo, 1024,
        retr_bf, nullptr, GM_BF16, GM_BF16, Bb * Ss, 1024, Hh, nullptr, nullptr);

    // 8) read-gate hidden  [8192 x 512], K = 2048 concat
    gemm_bf16_kernel<<<dim3(4, 64), 256, 0, stream>>>(
        hs_bf, retr_bf, Hh, wtRG, brg1, brg1, 512,
        rg_h, nullptr, GM_BF16S, GM_BF16S, Bb * Ss, 512, 2 * Hh, nullptr, nullptr);

    // 9) write-gate head
    gate2_kernel<<<Bb * Ss / 4, 256, 0, stream>>>(wg_h, Wwg2, bwg2, wg_row, Bb * Ss);

    // 10) residual + read-gate + layernorm
    out_ln_kernel<<<Bb * Ss, 256, 0, stream>>>(
        hs, retr_bf, rg_h, Wrg2, brg2, ln_g, ln_b, out_main);

    // 11) compressor layer 1  [2048 x 1024], K = 4096
    gemm_bf16_kernel<<<dim3(8, 16), 256, 0, stream>>>(
        hs_bf, hs_bf, CRr * Hh, wtC1, bc1, bc1, 1024,
        comp_h, nullptr, GM_BF16S, GM_BF16S, Bb * Ll, 1024, CRr * Hh, nullptr, nullptr);

    // 12) compressor layer 2 -> gated circular scatter into out_bank
    gemm_bf16_kernel<<<dim3(8, 16), 256, 0, stream>>>(
        comp_h, comp_h, Hh, wtC2, bc2, bc2, 1024,
        out_bank, nullptr, GM_F32G, GM_F32G, Bb * Ll, 1024, Hh, wp, wg_row);

    // 13) copy unwritten rows + mask + ptr
    bankfix_kernel<<<Bb * Mm, 256, 0, stream>>>(
        bank, mask, wp, out_bank, out_mask, out_ptr);
}

// Round 11
// 527.969 us; speedup vs baseline: 4.3754x; 1.0046x over previous
//
#include <hip/hip_runtime.h>
#include <hip/hip_bf16.h>

// Problem constants
#define Bb 4
#define Ss 2048
#define Hh 1024
#define Mm 1024
#define NHh 16
#define DHh 64
#define CRr 4
#define Ll (Ss / CRr)          // 512

#define SC2 0.18033688f        // 0.125 * log2(e)

typedef __attribute__((ext_vector_type(8))) short short8;    // 8 bf16
typedef __attribute__((ext_vector_type(4))) float f32x4;
typedef __attribute__((ext_vector_type(16))) float f32x16;

typedef __attribute__((address_space(1))) const unsigned int g_u32;
typedef __attribute__((address_space(3))) unsigned int l_u32;

__device__ inline void gload_lds16(const void* g, void* l) {
    __builtin_amdgcn_global_load_lds((g_u32*)g, (l_u32*)l, 16, 0, 0);
}

__device__ inline unsigned short f2bf(float x) {
    unsigned int u = __builtin_bit_cast(unsigned int, x);
    unsigned int r = u + 0x7FFFu + ((u >> 16) & 1u);   // RNE
    return (unsigned short)(r >> 16);
}
__device__ inline float bf2f(unsigned short u) {
    return __builtin_bit_cast(float, (unsigned int)u << 16);
}
__device__ inline unsigned int cvtpk_bf16(float lo, float hi2) {
    unsigned int r;
    asm("v_cvt_pk_bf16_f32 %0, %1, %2" : "=v"(r) : "v"(lo), "v"(hi2));
    return r;
}
__device__ inline f32x16 zero16() {
    f32x16 v;
    #pragma unroll
    for (int i = 0; i < 16; ++i) v[i] = 0.0f;
    return v;
}
// LDS fragment read with XOR chunk swizzle (rows are 128B; slot = 16B unit)
__device__ inline short8 lds_frag(const unsigned short* base, int row, int slot) {
    return *(const short8*)((const char*)base + row * 128 + ((slot ^ (row & 7)) << 4));
}

// ---------------------------------------------------------------------------
// Fused f32 -> bf16 cast for hs and bank + mask->bias (8 elems / thread)
// ---------------------------------------------------------------------------
#define N8_HS  (Bb * Ss * Hh / 8)    // 1048576
#define N8_BK  (Bb * Mm * Hh / 8)    // 524288
#define N8_MB  (Bb * Mm / 8)         // 512
__global__ __launch_bounds__(256) void cast2_kernel(
    const float* __restrict__ hs, const float* __restrict__ bank,
    const unsigned char* __restrict__ mask,
    unsigned short* __restrict__ hs_bf, unsigned short* __restrict__ bank_bf,
    float* __restrict__ bias_arr)
{
    int i = blockIdx.x * 256 + threadIdx.x;
    if (i >= N8_HS + N8_BK) {                     // mask -> additive bias tail
        i -= N8_HS + N8_BK;
        if (i < N8_MB) {
            #pragma unroll
            for (int j = 0; j < 8; ++j)
                bias_arr[i * 8 + j] = mask[i * 8 + j] ? 0.0f : -1.0e30f;
        }
        return;
    }
    const float* src; unsigned short* dst;
    if (i < N8_HS) { src = hs; dst = hs_bf; }
    else           { src = bank; dst = bank_bf; i -= N8_HS; }
    const float4* p = reinterpret_cast<const float4*>(src) + (size_t)i * 2;
    float4 a = p[0], b = p[1];
    uint4 o;
    o.x = (unsigned)f2bf(a.x) | ((unsigned)f2bf(a.y) << 16);
    o.y = (unsigned)f2bf(a.z) | ((unsigned)f2bf(a.w) << 16);
    o.z = (unsigned)f2bf(b.x) | ((unsigned)f2bf(b.y) << 16);
    o.w = (unsigned)f2bf(b.z) | ((unsigned)f2bf(b.w) << 16);
    *reinterpret_cast<uint4*>(dst + (size_t)i * 8) = o;
}

// ---------------------------------------------------------------------------
// All weight transposes in ONE kernel: W[K][N] f32 -> Wt[N][K] bf16.
// ---------------------------------------------------------------------------
__global__ __launch_bounds__(256) void transpose_all_kernel(
    const float* __restrict__ Wq, const float* __restrict__ Wwg1,
    const float* __restrict__ Wk, const float* __restrict__ Wv,
    const float* __restrict__ Wo, const float* __restrict__ Wrg1,
    const float* __restrict__ Wc1, const float* __restrict__ Wc2,
    unsigned short* wtQW, unsigned short* wtKV, unsigned short* wtO,
    unsigned short* wtRG, unsigned short* wtC1, unsigned short* wtC2)
{
    int bid = blockIdx.x;
    const float* src; unsigned short* dst; int K, N;
    if (bid < 1024)      { src = Wq;   dst = wtQW;              K = 1024; N = 1024; }
    else if (bid < 1536) { src = Wwg1; dst = wtQW + 1048576;    K = 1024; N = 512;  bid -= 1024; }
    else if (bid < 2560) { src = Wk;   dst = wtKV;              K = 1024; N = 1024; bid -= 1536; }
    else if (bid < 3584) { src = Wv;   dst = wtKV + 1048576;    K = 1024; N = 1024; bid -= 2560; }
    else if (bid < 4608) { src = Wo;   dst = wtO;               K = 1024; N = 1024; bid -= 3584; }
    else if (bid < 5632) { src = Wrg1; dst = wtRG;              K = 2048; N = 512;  bid -= 4608; }
    else if (bid < 9728) { src = Wc1;  dst = wtC1;              K = 4096; N = 1024; bid -= 5632; }
    else                 { src = Wc2;  dst = wtC2;              K = 1024; N = 1024; bid -= 9728; }
    const int ntx = N >> 5;
    const int k0 = (bid / ntx) * 32, n0 = (bid % ntx) * 32;

    __shared__ float tile[32][33];
    const int tx = threadIdx.x & 31, ty = threadIdx.x >> 5;
    #pragma unroll
    for (int r = 0; r < 32; r += 8)
        tile[r + ty][tx] = src[(size_t)(k0 + r + ty) * N + n0 + tx];
    __syncthreads();
    #pragma unroll
    for (int r = 0; r < 32; r += 8)
        dst[(size_t)(n0 + r + ty) * K + k0 + tx] = f2bf(tile[tx][r + ty]);
}

// ---------------------------------------------------------------------------
// BF16 MFMA GEMM (NT), dual output regions split at column N1.
// modes: 0=bf16, 1=bf16+SiLU, 2=bf16 transposed [b][d][key] (V),
//        3=f32 gated circular-scatter into bank (c2).
// ---------------------------------------------------------------------------
#define GM_BF16  0
#define GM_BF16S 1
#define GM_BF16T 2
#define GM_F32G  3

__global__ __launch_bounds__(256) void gemm_bf16_kernel(
    const unsigned short* __restrict__ A1, const unsigned short* __restrict__ A2,
    int K1, const unsigned short* __restrict__ Wt,
    const float* __restrict__ bias1, const float* __restrict__ bias2, int N1,
    void* out1, void* out2, int mode1, int mode2,
    int Mdim, int Ntot, int Kdim,
    const int* __restrict__ wp_ptr, const float* __restrict__ wg_row)
{
    __shared__ __align__(16) unsigned short As[128 * 64];
    __shared__ __align__(16) unsigned short Bs[128 * 64];

    const int t = threadIdx.x;
    const int l = t & 63;
    const int w = t >> 6;

    // XCD-aware swizzle (all grids have nwg % 8 == 0)
    const int nx = gridDim.x;
    const int nwg = nx * gridDim.y;
    const int bid0 = blockIdx.y * nx + blockIdx.x;
    const int swz = (nwg & 7) ? bid0 : ((bid0 & 7) * (nwg >> 3) + (bid0 >> 3));
    const int bm = (swz / nx) * 128;
    const int bn = (swz % nx) * 128;

    const int m_off = (w >> 1) * 64;
    const int n_off = (w & 1) * 64;
    const int K2 = Kdim - K1;

    f32x4 acc[4][4];
    const f32x4 z = {0.f, 0.f, 0.f, 0.f};
    #pragma unroll
    for (int i = 0; i < 4; ++i)
        #pragma unroll
        for (int j = 0; j < 4; ++j) acc[i][j] = z;

    for (int kt = 0; kt < Kdim; kt += 64) {
        __syncthreads();
        const unsigned short* Ap; int rsA, kl;
        if (kt < K1) { Ap = A1; rsA = K1; kl = kt; }
        else         { Ap = A2; rsA = K2; kl = kt - K1; }
        #pragma unroll
        for (int i = 0; i < 4; ++i) {
            const int c = i * 256 + t;
            const int row = c >> 3;
            const int p = (c & 7) ^ (row & 7);
            gload_lds16(Ap + (size_t)(bm + row) * rsA + kl + p * 8,
                        (char*)As + c * 16);
            gload_lds16(Wt + (size_t)(bn + row) * Kdim + kt + p * 8,
                        (char*)Bs + c * 16);
        }
        __syncthreads();
        #pragma unroll
        for (int kk = 0; kk < 2; ++kk) {
            short8 af[4], bfr[4];
            #pragma unroll
            for (int i = 0; i < 4; ++i) {
                af[i]  = lds_frag(As, m_off + i * 16 + (l & 15), kk * 4 + (l >> 4));
                bfr[i] = lds_frag(Bs, n_off + i * 16 + (l & 15), kk * 4 + (l >> 4));
            }
            #pragma unroll
            for (int i = 0; i < 4; ++i)
                #pragma unroll
                for (int j = 0; j < 4; ++j)
                    acc[i][j] = __builtin_amdgcn_mfma_f32_16x16x32_bf16(
                        af[i], bfr[j], acc[i][j], 0, 0, 0);
        }
    }

    // gated-scatter precompute (c2 only)
    float gg[16]; int wpv = 0;
    if (mode1 == GM_F32G) {
        wpv = *wp_ptr;
        #pragma unroll
        for (int i = 0; i < 4; ++i)
            #pragma unroll
            for (int r = 0; r < 4; ++r) {
                const int row = bm + m_off + i * 16 + (l >> 4) * 4 + r;
                gg[i * 4 + r] = 0.25f * (wg_row[4 * row] + wg_row[4 * row + 1] +
                                         wg_row[4 * row + 2] + wg_row[4 * row + 3]);
            }
    }

    #pragma unroll
    for (int j = 0; j < 4; ++j) {
        const int col = bn + n_off + j * 16 + (l & 15);
        const bool sec = (col >= N1);                 // uniform per j (N1 % 16 == 0)
        const int cl = sec ? col - N1 : col;
        const int mode = sec ? mode2 : mode1;
        const float bj = sec ? bias2[cl] : bias1[cl];
        const int nd = sec ? (Ntot - N1) : N1;
        if (mode == GM_BF16T) {
            unsigned short* ob = (unsigned short*)out2;
            #pragma unroll
            for (int i = 0; i < 4; ++i) {
                const int row0 = bm + m_off + i * 16 + (l >> 4) * 4;
                const int bidx = row0 >> 10, key = row0 & 1023;
                ushort4 pk4;
                pk4.x = f2bf(acc[i][j][0] + bj);
                pk4.y = f2bf(acc[i][j][1] + bj);
                pk4.z = f2bf(acc[i][j][2] + bj);
                pk4.w = f2bf(acc[i][j][3] + bj);
                *(ushort4*)(ob + ((size_t)bidx << 20) + (size_t)cl * 1024 + key) = pk4;
            }
        } else if (mode == GM_F32G) {
            float* ob = (float*)out1;
            #pragma unroll
            for (int i = 0; i < 4; ++i)
                #pragma unroll
                for (int r = 0; r < 4; ++r) {
                    const int row = bm + m_off + i * 16 + (l >> 4) * 4 + r;
                    const int bb = row >> 9, lx = row & 511;
                    const int m = (wpv + lx) & 1023;
                    ob[((size_t)(bb * 1024 + m)) * 1024 + col] =
                        (acc[i][j][r] + bj) * gg[i * 4 + r];
                }
        } else {
            unsigned short* ob = (unsigned short*)(sec ? out2 : out1);
            #pragma unroll
            for (int i = 0; i < 4; ++i)
                #pragma unroll
                for (int r = 0; r < 4; ++r) {
                    const int row = bm + m_off + i * 16 + (l >> 4) * 4 + r;
                    float v0 = acc[i][j][r] + bj;
                    if (mode == GM_BF16S) v0 = v0 / (1.0f + __expf(-v0));
                    ob[(size_t)row * nd + cl] = f2bf(v0);
                }
        }
    }
}

// ---------------------------------------------------------------------------
// Flash attention: swapped-QK^T in-register softmax, exp2 domain, defer-max,
// double-buffered K/V staging (raw s_barrier + counted vmcnt), XCD-grouped
// grid. Mask-bias row staged in LDS so the ONLY in-loop VMEM ops are the 4
// staging loads (keeps vmcnt(4) semantics exact — no forced drains).
// grid = 1024 (1D), 256 thr (4 waves x 32 q-rows = 128 q/block).
// ---------------------------------------------------------------------------
__global__ __launch_bounds__(256) void attn_mfma_kernel(
    const unsigned short* __restrict__ q, const unsigned short* __restrict__ k,
    const unsigned short* __restrict__ vt, const float* __restrict__ bias_arr,
    unsigned short* __restrict__ out)
{
    // XCD-bijective decode: xcd = bid&7 gets hb groups [8*xcd, 8*xcd+7]
    const int bid = blockIdx.x;
    const int xcd = bid & 7, jj = bid >> 3;          // jj in 0..127
    const int hb = xcd * 8 + (jj >> 4);              // 0..63
    const int qt = jj & 15;
    const int b = hb >> 4, h = hb & 15;

    const int t = threadIdx.x, l = t & 63, w = t >> 6;
    const int lq = l & 31, hi = l >> 5;

    __shared__ __align__(16) unsigned short Ks[2][64 * 64];
    __shared__ __align__(16) unsigned short Vs[2][64 * 64];
    __shared__ __align__(16) float Bls[Mm];          // this batch's bias row (4 KB)

    // ---- stage bias row to LDS (one float4/thread) ----
    {
        const float4 bv4 = *(const float4*)(bias_arr + b * Mm + t * 4);
        *(float4*)&Bls[t * 4] = bv4;
    }
    asm volatile("s_waitcnt lgkmcnt(0)" ::: "memory");   // write landed (pub at 1st barrier)

    // staging bases (chunk 0); K advances 64*Hh elems/chunk, Vt advances 64
    const int c0 = t, c1 = t + 256;
    const int r0 = c0 >> 3, s0 = c0 & 7;
    const int r1 = c1 >> 3, s1 = c1 & 7;
    const unsigned short* kb0 = k + ((size_t)(b * Mm + r0)) * Hh + h * 64 + ((s0 ^ (r0 & 7)) * 8);
    const unsigned short* kb1 = k + ((size_t)(b * Mm + r1)) * Hh + h * 64 + ((s1 ^ (r1 & 7)) * 8);
    const unsigned short* vb0 = vt + ((size_t)b << 20) + (size_t)(h * 64 + r0) * Mm + ((s0 ^ (r0 & 7)) * 8);
    const unsigned short* vb1 = vt + ((size_t)b << 20) + (size_t)(h * 64 + r1) * Mm + ((s1 ^ (r1 & 7)) * 8);

#define ATTN_STAGE(cc, bf) do {                                          \
    const size_t ko_ = (size_t)(cc) * 64 * Hh;                           \
    const int vo_ = (cc) * 64;                                           \
    gload_lds16(kb0 + ko_, (char*)Ks[bf] + c0 * 16);                     \
    gload_lds16(kb1 + ko_, (char*)Ks[bf] + c1 * 16);                     \
    gload_lds16(vb0 + vo_, (char*)Vs[bf] + c0 * 16);                     \
    gload_lds16(vb1 + vo_, (char*)Vs[bf] + c1 * 16);                     \
} while (0)

    // Q fragments in registers (reused across all 16 chunks)
    short8 qf[4];
    {
        const int qg = qt * 128 + w * 32 + lq;
        const unsigned short* qp = q + ((size_t)(b * Ss + qg)) * Hh + h * 64 + hi * 8;
        #pragma unroll
        for (int tt = 0; tt < 4; ++tt) qf[tt] = *(const short8*)(qp + tt * 16);
    }

    f32x16 oacc0 = zero16(), oacc1 = zero16();
    float m_run = -1.0e38f, l_run = 0.0f;

    ATTN_STAGE(0, 0);

    for (int c = 0; c < Mm / 64; ++c) {
        const int cur = c & 1;
        const int kc = c * 64;
        if (c < 15) {
            ATTN_STAGE(c + 1, cur ^ 1);
            asm volatile("s_waitcnt vmcnt(4)" ::: "memory");  // chunk c loads done
        } else {
            asm volatile("s_waitcnt vmcnt(0)" ::: "memory");
        }
        __builtin_amdgcn_s_barrier();
        const unsigned short* Kb = Ks[cur];
        const unsigned short* Vb = Vs[cur];

        // ---- S^T = K . Q ----
        f32x16 st0 = zero16(), st1 = zero16();
        #pragma unroll
        for (int tt = 0; tt < 4; ++tt) {
            short8 k0 = lds_frag(Kb, lq,      2 * tt + hi);
            short8 k1 = lds_frag(Kb, 32 + lq, 2 * tt + hi);
            st0 = __builtin_amdgcn_mfma_f32_32x32x16_bf16(k0, qf[tt], st0, 0, 0, 0);
            st1 = __builtin_amdgcn_mfma_f32_32x32x16_bf16(k1, qf[tt], st1, 0, 0, 0);
        }

        // ---- scale to exp2 domain + additive mask bias (bias from LDS) ----
        float sv[32];
        #pragma unroll
        for (int kb = 0; kb < 2; ++kb) {
            const f32x16 stv = kb ? st1 : st0;
            #pragma unroll
            for (int g = 0; g < 4; ++g) {
                const float4 bf4 = *(const float4*)&Bls[kc + kb * 32 + 8 * g + 4 * hi];
                sv[kb * 16 + g * 4 + 0] = fmaf(stv[g * 4 + 0], SC2, bf4.x);
                sv[kb * 16 + g * 4 + 1] = fmaf(stv[g * 4 + 1], SC2, bf4.y);
                sv[kb * 16 + g * 4 + 2] = fmaf(stv[g * 4 + 2], SC2, bf4.z);
                sv[kb * 16 + g * 4 + 3] = fmaf(stv[g * 4 + 3], SC2, bf4.w);
            }
        }

        // ---- max (tree) + cross-half ----
        float mx = fmaxf(sv[0], fmaxf(sv[1], sv[2]));
        #pragma unroll
        for (int i = 3; i < 31; i += 2) mx = fmaxf(mx, fmaxf(sv[i], sv[i + 1]));
        mx = fmaxf(mx, sv[31]);
        mx = fmaxf(mx, __shfl_xor(mx, 32));

        // ---- defer-max rescale ----
        if (!__all(mx <= m_run + 10.0f)) {
            const float m_new = fmaxf(m_run, mx);
            const float fac = exp2f(m_run - m_new);
            m_run = m_new;
            l_run *= fac;
            #pragma unroll
            for (int i = 0; i < 16; ++i) { oacc0[i] *= fac; oacc1[i] *= fac; }
        }

        // ---- P = exp2(s - m), sum ----
        float psum = 0.0f;
        #pragma unroll
        for (int i = 0; i < 32; ++i) {
            const float pv = exp2f(sv[i] - m_run);
            sv[i] = pv; psum += pv;
        }
        psum += __shfl_xor(psum, 32);
        l_run += psum;

        // ---- pack P into 4 MFMA fragments ----
        short8 pf[4];
        #pragma unroll
        for (int kb = 0; kb < 2; ++kb) {
            #pragma unroll
            for (int gp = 0; gp < 2; ++gp) {
                const float* pp = &sv[kb * 16 + gp * 8];
                unsigned int u  = cvtpk_bf16(pp[0], pp[1]);
                unsigned int v2 = cvtpk_bf16(pp[2], pp[3]);
                unsigned int w2 = cvtpk_bf16(pp[4], pp[5]);
                unsigned int z2 = cvtpk_bf16(pp[6], pp[7]);
                unsigned int su = __shfl_xor(u, 32),  sv2 = __shfl_xor(v2, 32);
                unsigned int sw = __shfl_xor(w2, 32), sz  = __shfl_xor(z2, 32);
                const bool low = (hi == 0);
                union { unsigned int d[4]; short8 s; } fr;
                fr.d[0] = low ? u   : sw;
                fr.d[1] = low ? v2  : sz;
                fr.d[2] = low ? su  : w2;
                fr.d[3] = low ? sv2 : z2;
                pf[kb * 2 + gp] = fr.s;
            }
        }

        // ---- PV: O^T = V^T . P ----
        #pragma unroll
        for (int ks = 0; ks < 4; ++ks) {
            short8 v0 = lds_frag(Vb, lq,      2 * ks + hi);
            short8 v1 = lds_frag(Vb, 32 + lq, 2 * ks + hi);
            oacc0 = __builtin_amdgcn_mfma_f32_32x32x16_bf16(v0, pf[ks], oacc0, 0, 0, 0);
            oacc1 = __builtin_amdgcn_mfma_f32_32x32x16_bf16(v1, pf[ks], oacc1, 0, 0, 0);
        }
        __builtin_amdgcn_s_barrier();   // all waves done reading buf[cur]
    }
#undef ATTN_STAGE

    const float inv = (l_run > 0.0f) ? 1.0f / l_run : 0.0f;
    const int qg = qt * 128 + w * 32 + lq;
    unsigned short* op = out + ((size_t)(b * Ss + qg)) * Hh + h * 64;
    #pragma unroll
    for (int db = 0; db < 2; ++db) {
        const f32x16 oa = db ? oacc1 : oacc0;
        #pragma unroll
        for (int g = 0; g < 4; ++g) {
            const int d0 = db * 32 + 8 * g + 4 * hi;
            ushort4 pk4;
            pk4.x = f2bf(oa[g * 4 + 0] * inv);
            pk4.y = f2bf(oa[g * 4 + 1] * inv);
            pk4.z = f2bf(oa[g * 4 + 2] * inv);
            pk4.w = f2bf(oa[g * 4 + 3] * inv);
            *(ushort4*)(op + d0) = pk4;
        }
    }
}

// ---------------------------------------------------------------------------
// Gate head (write gate): g[row] = sigmoid( wg_h[row,0:512] . w2 + b2 )
// ---------------------------------------------------------------------------
__global__ __launch_bounds__(256) void gate2_kernel(
    const unsigned short* __restrict__ h, const float* __restrict__ w2,
    const float* __restrict__ b2, float* __restrict__ outg, int R)
{
    const int wid = threadIdx.x / 64;
    const int lane = threadIdx.x % 64;
    const int row = blockIdx.x * 4 + wid;
    if (row >= R) return;
    short8 hv = *(const short8*)(h + (size_t)row * 512 + lane * 8);
    float4 w0 = *(const float4*)(w2 + lane * 8);
    float4 w1 = *(const float4*)(w2 + lane * 8 + 4);
    float s = bf2f((unsigned short)hv[0]) * w0.x + bf2f((unsigned short)hv[1]) * w0.y +
              bf2f((unsigned short)hv[2]) * w0.z + bf2f((unsigned short)hv[3]) * w0.w +
              bf2f((unsigned short)hv[4]) * w1.x + bf2f((unsigned short)hv[5]) * w1.y +
              bf2f((unsigned short)hv[6]) * w1.z + bf2f((unsigned short)hv[7]) * w1.w;
    #pragma unroll
    for (int o = 1; o < 64; o <<= 1) s += __shfl_xor(s, o);
    if (lane == 0) outg[row] = 1.0f / (1.0f + __expf(-(s + b2[0])));
}

// ---------------------------------------------------------------------------
// out = LayerNorm(hs + rg*retr) with rg computed in-kernel from rg_h.
// ---------------------------------------------------------------------------
__global__ __launch_bounds__(256) void out_ln_kernel(
    const float* __restrict__ hs, const unsigned short* __restrict__ retr,
    const unsigned short* __restrict__ rg_h, const float* __restrict__ Wrg2,
    const float* __restrict__ brg2, const float* __restrict__ gam,
    const float* __restrict__ bet, float* __restrict__ out)
{
    const int row = blockIdx.x;
    const int t = threadIdx.x;
    const int wid = t >> 6, lane = t & 63;

    // ---- read-gate dot: rg_h[row][0:512] . Wrg2 ----
    const unsigned int hv = *(const unsigned int*)(rg_h + (size_t)row * 512 + t * 2);
    const float2 wv = *(const float2*)(Wrg2 + t * 2);
    float sd = bf2f((unsigned short)(hv & 0xffffu)) * wv.x +
               bf2f((unsigned short)(hv >> 16)) * wv.y;
    #pragma unroll
    for (int o = 1; o < 64; o <<= 1) sd += __shfl_xor(sd, o);
    __shared__ float rsd[4];
    if (lane == 0) rsd[wid] = sd;
    __syncthreads();
    const float r = 1.0f / (1.0f + __expf(-(rsd[0] + rsd[1] + rsd[2] + rsd[3] + brg2[0])));

    // ---- residual + LN ----
    float x[4];
    float s = 0.0f, s2 = 0.0f;
    #pragma unroll
    for (int i = 0; i < 4; ++i) {
        const int col = t + i * 256;
        const float val = hs[(size_t)row * Hh + col] +
                          r * bf2f(retr[(size_t)row * Hh + col]);
        x[i] = val; s += val; s2 += val * val;
    }
    #pragma unroll
    for (int o = 1; o < 64; o <<= 1) { s += __shfl_xor(s, o); s2 += __shfl_xor(s2, o); }
    __shared__ float rs[4], rs2[4];
    if (lane == 0) { rs[wid] = s; rs2[wid] = s2; }
    __syncthreads();
    const float tot = rs[0] + rs[1] + rs[2] + rs[3];
    const float tot2 = rs2[0] + rs2[1] + rs2[2] + rs2[3];
    const float mu = tot * (1.0f / Hh);
    const float var = tot2 * (1.0f / Hh) - mu * mu;
    const float rstd = rsqrtf(var + 1e-5f);
    #pragma unroll
    for (int i = 0; i < 4; ++i) {
        const int col = t + i * 256;
        out[(size_t)row * Hh + col] = (x[i] - mu) * rstd * gam[col] + bet[col];
    }
}

// ---------------------------------------------------------------------------
// Copy unwritten bank rows + emit new_mask and new_ptr.
// ---------------------------------------------------------------------------
__global__ __launch_bounds__(256) void bankfix_kernel(
    const float* __restrict__ bank, const unsigned char* __restrict__ mask,
    const int* __restrict__ wp_ptr, float* __restrict__ out_bank,
    float* __restrict__ out_mask, float* __restrict__ out_ptr)
{
    const int row = blockIdx.x;          // b*M + m
    const int wp = *wp_ptr;
    const int m = row & 1023;
    int rel = m - (wp & 1023);
    if (rel < 0) rel += Mm;
    const bool written = rel < Ll;
    if (!written) {
        const int col = threadIdx.x * 4;
        *(float4*)(out_bank + (size_t)row * Hh + col) =
            *(const float4*)(bank + (size_t)row * Hh + col);
    }
    if (threadIdx.x == 0) out_mask[row] = (mask[row] != 0 || written) ? 1.0f : 0.0f;
    if (row == 0 && threadIdx.x == 0) out_ptr[0] = (float)((wp + Ll) % Mm);
}

// ---------------------------------------------------------------------------
// Launch
// ---------------------------------------------------------------------------
extern "C" void kernel_launch(void* const* d_in, const int* in_sizes, int n_in,
                              void* d_out, int out_size, void* d_ws, size_t ws_size,
                              hipStream_t stream)
{
    const float* hs   = (const float*)d_in[0];
    const float* bank = (const float*)d_in[1];
    const unsigned char* mask = (const unsigned char*)d_in[2];
    const int*   wp   = (const int*)d_in[3];
    const float* Wc1 = (const float*)d_in[4];  const float* bc1 = (const float*)d_in[5];
    const float* Wc2 = (const float*)d_in[6];  const float* bc2 = (const float*)d_in[7];
    const float* Wq  = (const float*)d_in[8];  const float* bq  = (const float*)d_in[9];
    const float* Wk  = (const float*)d_in[10]; const float* bk  = (const float*)d_in[11];
    const float* Wv  = (const float*)d_in[12]; const float* bv  = (const float*)d_in[13];
    const float* Wo  = (const float*)d_in[14]; const float* bo  = (const float*)d_in[15];
    const float* Wwg1 = (const float*)d_in[16]; const float* bwg1 = (const float*)d_in[17];
    const float* Wwg2 = (const float*)d_in[18]; const float* bwg2 = (const float*)d_in[19];
    const float* Wrg1 = (const float*)d_in[20]; const float* brg1 = (const float*)d_in[21];
    const float* Wrg2 = (const float*)d_in[22]; const float* brg2 = (const float*)d_in[23];
    const float* ln_g = (const float*)d_in[24]; const float* ln_b = (const float*)d_in[25];

    float* out_main = (float*)d_out;                       // B*S*H floats (32 MiB)
    float* out_bank = out_main + (size_t)Bb * Ss * Hh;     // B*M*H floats (16 MiB)
    float* out_mask = out_bank + (size_t)Bb * Mm * Hh;     // B*M
    float* out_ptr  = out_mask + (size_t)Bb * Mm;          // 1

    // ---- d_out as scratch (all dead before the final writes) ----
    unsigned short* q_bf   = (unsigned short*)out_main;
    unsigned short* att_bf = (unsigned short*)out_main + 8388608;
    unsigned short* wtQW = (unsigned short*)out_bank;                // 1,572,864 sh
    unsigned short* wtO  = (unsigned short*)out_bank + 1572864;      // 1,048,576 sh
    unsigned short* wtRG = (unsigned short*)out_bank + 2621440;      // 1,048,576 sh
    unsigned short* wtC1 = (unsigned short*)out_bank + 3670016;      // ends 7,864,320 < 8,388,608 ✓

    // ---- workspace arena (top usage 73.5 MB) ----
    char* W = (char*)d_ws;
    unsigned short* hs_bf   = (unsigned short*)(W + 0);          // 16 MiB
    unsigned short* bank_bf = (unsigned short*)(W + 16777216);   // 8 MiB (dead after KV)
    unsigned short* rg_h    = (unsigned short*)(W + 16777216);   // reuse (8 MiB)
    unsigned short* retr_bf = (unsigned short*)(W + 25165824);   // 16 MiB
    unsigned short* k_bf    = (unsigned short*)(W + 41943040);   // 8 MiB
    unsigned short* vt_bf   = (unsigned short*)(W + 50331648);   // 8 MiB (dead after attn)
    unsigned short* comp_h  = (unsigned short*)(W + 50331648);   // reuse (4 MiB)
    unsigned short* wg_h    = (unsigned short*)(W + 58720256);   // 8 MiB
    unsigned short* wtC2    = (unsigned short*)(W + 67108864);   // 2 MiB
    unsigned short* wtKV    = (unsigned short*)(W + 69206016);   // 4 MiB
    float* wg_row   = (float*)(W + 73400320);                    // 32 KiB
    float* bias_arr = (float*)(W + 73433088);                    // 16 KiB

    // 1) casts + mask bias (fused)
    cast2_kernel<<<(N8_HS + N8_BK + N8_MB + 255) / 256, 256, 0, stream>>>(
        hs, bank, mask, hs_bf, bank_bf, bias_arr);

    // 2) all weight transposes
    transpose_all_kernel<<<10752, 256, 0, stream>>>(
        Wq, Wwg1, Wk, Wv, Wo, Wrg1, Wc1, Wc2,
        wtQW, wtKV, wtO, wtRG, wtC1, wtC2);

    // 3) fused Q + write-gate hidden   [8192 x 1536]
    gemm_bf16_kernel<<<dim3(12, 64), 256, 0, stream>>>(
        hs_bf, hs_bf, Hh, wtQW, bq, bwg1, 1024,
        q_bf, wg_h, GM_BF16, GM_BF16S, Bb * Ss, 1536, Hh, nullptr, nullptr);

    // 4) fused K + V (V transposed)    [4096 x 2048]
    gemm_bf16_kernel<<<dim3(16, 32), 256, 0, stream>>>(
        bank_bf, bank_bf, Hh, wtKV, bk, bv, 1024,
        k_bf, vt_bf, GM_BF16, GM_BF16T, Bb * Mm, 2048, Hh, nullptr, nullptr);

    // 5) attention (1D XCD-grouped grid)
    attn_mfma_kernel<<<1024, 256, 0, stream>>>(
        q_bf, k_bf, vt_bf, bias_arr, att_bf);

    // 6) output projection
    gemm_bf16_kernel<<<dim3(8, 64), 256, 0, stream>>>(
        att_bf, att_bf, Hh, wtO, bo, bo, 1024,
        retr_bf, nullptr, GM_BF16, GM_BF16, Bb * Ss, 1024, Hh, nullptr, nullptr);

    // 7) read-gate hidden  [8192 x 512], K = 2048 concat
    gemm_bf16_kernel<<<dim3(4, 64), 256, 0, stream>>>(
        hs_bf, retr_bf, Hh, wtRG, brg1, brg1, 512,
        rg_h, nullptr, GM_BF16S, GM_BF16S, Bb * Ss, 512, 2 * Hh, nullptr, nullptr);

    // 8) write-gate head
    gate2_kernel<<<Bb * Ss / 4, 256, 0, stream>>>(wg_h, Wwg2, bwg2, wg_row, Bb * Ss);

    // 9) residual + read-gate + layernorm
    out_ln_kernel<<<Bb * Ss, 256, 0, stream>>>(
        hs, retr_bf, rg_h, Wrg2, brg2, ln_g, ln_b, out_main);

    // 10) compressor layer 1  [2048 x 1024], K = 4096
    gemm_bf16_kernel<<<dim3(8, 16), 256, 0, stream>>>(
        hs_bf, hs_bf, CRr * Hh, wtC1, bc1, bc1, 1024,
        comp_h, nullptr, GM_BF16S, GM_BF16S, Bb * Ll, 1024, CRr * Hh, nullptr, nullptr);

    // 11) compressor layer 2 -> gated circular scatter into out_bank
    gemm_bf16_kernel<<<dim3(8, 16), 256, 0, stream>>>(
        comp_h, comp_h, Hh, wtC2, bc2, bc2, 1024,
        out_bank, nullptr, GM_F32G, GM_F32G, Bb * Ll, 1024, Hh, wp, wg_row);

    // 12) copy unwritten rows + mask + ptr
    bankfix_kernel<<<Bb * Mm, 256, 0, stream>>>(
        bank, mask, wp, out_bank, out_mask, out_ptr);
}